// Round 13
// baseline (986.487 us; speedup 1.0000x reference)
//
#include <hip/hip_runtime.h>
#include <hip/hip_fp16.h>
#include <cmath>

// ---------------- problem constants ----------------
constexpr int IMH = 320, IMW = 320, NPIX = IMH * IMW, NC = 21;
constexpr int CP4 = 6;           // padded channels / 4  (24 values per row)
constexpr int DB = 5, DB1 = 6;   // bilateral lattice dim
constexpr int DS = 2, DS1 = 3;   // spatial lattice dim
constexpr int RB = NPIX * DB1;   // splat entries (bilateral) = 614400
constexpr int RS = NPIX * DS1;   // (spatial) = 307200
constexpr int TBS = 1 << 20;     // hash table slots (bilateral)
constexpr int TSS = 1 << 18;     // hash table slots (spatial)
constexpr int NBUCK = 1 << 16;   // spatial-sort buckets (c0,c1 low bytes)
constexpr int NW1 = (RB + RS) / 64;  // wave sums in the unified offset scan

// Combined lattice-value buffer layout (static partition):
//   bilateral: row 0 = sink, point m -> row m+1           (rows [0, RB])
//   spatial:   row RB+1 = sink, point m -> row RB+2+m     (rows [RB+1, ...])
// spatial neighbor n=-1 maps to RB+2+(-1) = RB+1 = sink automatically.

// epw entry packing (4B): low 17 bits = pixel index, high 15 bits = weight
// quantized to [0,32767] fixed point (abs err 3e-5 << fp16 chain rounding).

#define EMPTY_KEY 0xFFFFFFFFFFFFFFFFULL

__device__ __forceinline__ unsigned long long mix64(unsigned long long x) {
    x ^= x >> 33; x *= 0xff51afd7ed558ccdULL;
    x ^= x >> 33; x *= 0xc4ceb9fe1a85ec53ULL;
    x ^= x >> 33; return x;
}

// fp16 pack helpers: uint2 = 4 halves; math in fp32, storage fp16.
__device__ __forceinline__ float4 u2f(uint2 u) {
    __half2 a = *reinterpret_cast<__half2*>(&u.x);
    __half2 b = *reinterpret_cast<__half2*>(&u.y);
    float2 fa = __half22float2(a), fb = __half22float2(b);
    return make_float4(fa.x, fa.y, fb.x, fb.y);
}
__device__ __forceinline__ uint2 f2u(float4 v) {
    __half2 a = __floats2half2_rn(v.x, v.y);
    __half2 b = __floats2half2_rn(v.z, v.w);
    uint2 u;
    u.x = *reinterpret_cast<unsigned*>(&a);
    u.y = *reinterpret_cast<unsigned*>(&b);
    return u;
}

__device__ __forceinline__ unsigned pack_ew(int pix, float w) {
    int w15 = (int)lrintf(fminf(fmaxf(w, 0.f), 1.f) * 32767.f);
    return ((unsigned)w15 << 17) | (unsigned)pix;
}
__device__ __forceinline__ void unpack_ew(unsigned e, int& pix, float& w) {
    pix = (int)(e & 0x1FFFFu);
    w = (float)(e >> 17) * (1.0f / 32767.0f);
}

// ---------------- permutohedral embedding (matches reference op-for-op, f32) ----------------
template<int D>
__device__ void perm_embed(const float* f, float* bary, unsigned long long* pk) {
    constexpr int D1 = D + 1;
    float cf[D];
    #pragma unroll
    for (int i = 0; i < D; i++) {
        double s = sqrt(2.0 / 3.0) * (double)D1 / sqrt((double)((i + 1) * (i + 2)));
        cf[i] = f[i] * (float)s;
    }
    float csum[D];
    float acc = 0.f;
    #pragma unroll
    for (int i = D - 1; i >= 0; i--) { acc += cf[i]; csum[i] = acc; }
    float el[D1];
    el[0] = csum[0];
    #pragma unroll
    for (int i = 1; i < D; i++) el[i] = csum[i] - (float)i * cf[i - 1];
    el[D] = -(float)D * cf[D - 1];
    const float down = 1.0f / (float)D1;
    float rem0[D1]; int rank[D1]; int ssum = 0;
    #pragma unroll
    for (int i = 0; i < D1; i++) {
        float rd = rintf(el[i] * down);
        rem0[i] = rd * (float)D1;
        ssum += (int)rd;
    }
    float diff[D1];
    #pragma unroll
    for (int i = 0; i < D1; i++) diff[i] = el[i] - rem0[i];
    #pragma unroll
    for (int i = 0; i < D1; i++) {
        int r = 0;
        #pragma unroll
        for (int j = 0; j < D1; j++)
            r += (diff[j] > diff[i]) || ((diff[j] == diff[i]) && (j < i));
        rank[i] = r + ssum;
    }
    #pragma unroll
    for (int i = 0; i < D1; i++) {
        if (rank[i] < 0)      { rank[i] += D1; rem0[i] += (float)D1; }
        else if (rank[i] > D) { rank[i] -= D1; rem0[i] -= (float)D1; }
    }
    float b[D + 2];
    #pragma unroll
    for (int i = 0; i < D + 2; i++) b[i] = 0.f;
    #pragma unroll
    for (int i = 0; i < D1; i++) b[D - rank[i]]     += (el[i] - rem0[i]) * down;
    #pragma unroll
    for (int i = 0; i < D1; i++) b[D + 1 - rank[i]] -= (el[i] - rem0[i]) * down;
    b[0] += 1.0f + b[D + 1];
    #pragma unroll
    for (int i = 0; i < D1; i++) bary[i] = b[i];
    int key0[D];
    #pragma unroll
    for (int i = 0; i < D; i++) key0[i] = (int)rintf(rem0[i]);
    #pragma unroll
    for (int r = 0; r < D1; r++) {
        unsigned long long p = 0;
        #pragma unroll
        for (int i = 0; i < D; i++) {
            int c = key0[i] + ((rank[i] < D1 - r) ? r : r - D1);
            p |= ((unsigned long long)((unsigned)(c + 2048) & 0xFFFu)) << (12 * i);
        }
        pk[r] = p;
    }
}

__device__ __forceinline__ int key_code(unsigned long long k) {
    int c0 = (int)(k & 0xFFFULL);
    int c1 = (int)((k >> 12) & 0xFFFULL);
    return ((c0 & 0xFF) << 8) | (c1 & 0xFF);
}

// ---------------- hash table ----------------
// test-before-CAS insert (+ bucket histogram on CAS win). Slots are write-once
// (EMPTY->key, never mutated), so a plain load observing a non-empty key is
// authoritative; only an observed-EMPTY goes through atomicCAS (which re-checks
// coherently, so a stale EMPTY from L1 is safe). This keeps the ~72% duplicate
// insert attempts read-only: r12's 79 MB WRITE_SIZE was CAS sector-dirtying.
__device__ __forceinline__ int hash_insert_hist(unsigned long long* hk, int tmask,
                                                unsigned long long k, int* histbase) {
    int slot = (int)(mix64(k) & (unsigned long long)tmask);
    while (true) {
        unsigned long long v = hk[slot];
        if (v == k) return slot;
        if (v == EMPTY_KEY) {
            unsigned long long prev = atomicCAS(&hk[slot], EMPTY_KEY, k);
            if (prev == EMPTY_KEY) { atomicAdd(&histbase[key_code(k)], 1); return slot; }
            if (prev == k) return slot;
            // another key won this slot; keep probing
        }
        slot = (slot + 1) & tmask;
    }
}
__device__ __forceinline__ int hash_lookup(const unsigned long long* hk, const int* hid,
                                           int tmask, unsigned long long k) {
    int slot = (int)(mix64(k) & (unsigned long long)tmask);
    while (true) {
        unsigned long long v = hk[slot];
        if (v == k) return hid[slot];
        if (v == EMPTY_KEY) return -1;
        slot = (slot + 1) & tmask;
    }
}

// ---------------- build kernels ----------------
// one launch builds both lattices (hk = unified table: [0,TBS) bilateral, [TBS,+TSS) spatial)
// and accumulates the bucket histogram inline (hist halves: [0,NBUCK) b, [NBUCK,2N) s).
__global__ void build_both(const float* __restrict__ image, unsigned long long* hk,
                           int* os, float* wsv, int* hist) {
    int i = blockIdx.x * blockDim.x + threadIdx.x;
    if (i < NPIX) {
        int x = i % IMW, y = i / IMW;
        float f[DB];
        f[0] = (float)x / 80.0f;
        f[1] = (float)y / 80.0f;
        f[2] = image[i * 3 + 0] / 13.0f;
        f[3] = image[i * 3 + 1] / 13.0f;
        f[4] = image[i * 3 + 2] / 13.0f;
        float bary[DB1]; unsigned long long pk[DB1];
        perm_embed<DB>(f, bary, pk);
        #pragma unroll
        for (int r = 0; r < DB1; r++) {
            wsv[i * DB1 + r] = bary[r];
            os[i * DB1 + r] = hash_insert_hist(hk, TBS - 1, pk[r], hist);
        }
    } else if (i < 2 * NPIX) {
        int ip = i - NPIX;
        int x = ip % IMW, y = ip / IMW;
        float f[DS];
        f[0] = (float)x / 3.0f;
        f[1] = (float)y / 3.0f;
        float bary[DS1]; unsigned long long pk[DS1];
        perm_embed<DS>(f, bary, pk);
        #pragma unroll
        for (int r = 0; r < DS1; r++) {
            wsv[RB + ip * DS1 + r] = bary[r];
            os[RB + ip * DS1 + r] = hash_insert_hist(hk + TBS, TSS - 1, pk[r], hist + NBUCK);
        }
    }
}

// ---------------- barrier-free scan machinery ----------------
__global__ void scan_wave_partial(const int* __restrict__ count, int* incl, int* wsum, int n) {
    int idx = blockIdx.x * blockDim.x + threadIdx.x;
    int lane = threadIdx.x & 63;
    int v = (idx < n) ? count[idx] : 0;
    int s = v;
    #pragma unroll
    for (int d = 1; d < 64; d <<= 1) {
        int t = __shfl_up(s, d);
        if (lane >= d) s += t;
    }
    if (idx < n) incl[idx] = s;
    if (lane == 63) wsum[idx >> 6] = s;
}

__global__ void scan_partials_excl(int* w, int nw, int* total_out) {
    __shared__ int sh[256];
    __shared__ int run;
    if (threadIdx.x == 0) run = 0;
    __syncthreads();
    for (int basei = 0; basei < nw; basei += 256) {
        int idx = basei + threadIdx.x;
        int v = (idx < nw) ? w[idx] : 0;
        sh[threadIdx.x] = v;
        __syncthreads();
        for (int d = 1; d < 256; d <<= 1) {
            int t = (threadIdx.x >= d) ? sh[threadIdx.x - d] : 0;
            __syncthreads();
            sh[threadIdx.x] += t;
            __syncthreads();
        }
        int total = sh[255];
        if (idx < nw) w[idx] = run + sh[threadIdx.x] - v;
        __syncthreads();
        if (threadIdx.x == 0) run += total;
        __syncthreads();
    }
    if (total_out != nullptr && threadIdx.x == 0) *total_out = run;
}

__global__ void scan_finalize(int* off, const int* __restrict__ count,
                              const int* __restrict__ wsum, int n) {
    int idx = blockIdx.x * blockDim.x + threadIdx.x;
    if (idx < n) off[idx] = off[idx] - count[idx] + wsum[idx >> 6];
}

// ---------------- bucket-sorted compaction ----------------
__global__ void assign_both(const unsigned long long* __restrict__ hk, int* hid,
                            const int* __restrict__ histOff, int* histFill,
                            unsigned long long* uk_b, unsigned long long* uk_s) {
    int s = blockIdx.x * blockDim.x + threadIdx.x;
    if (s >= TBS + TSS) return;
    unsigned long long k = hk[s];
    if (k == EMPTY_KEY) return;
    int half = (s < TBS) ? 0 : NBUCK;
    int code = half + key_code(k);
    int id = histOff[code] + atomicAdd(&histFill[code], 1);
    hid[s] = id;
    if (s < TBS) uk_b[id] = k; else uk_s[id] = k;
}

// unified os remap + cntr histogram (cntr slots: [0,RB) bilateral ids, [RB,RB+RS) spatial)
__global__ void os_count_both(int* os, const int* __restrict__ hid, int* cntr) {
    int i = blockIdx.x * blockDim.x + threadIdx.x;
    if (i >= RB + RS) return;
    if (i < RB) {
        int id = hid[os[i]];
        os[i] = id;
        atomicAdd(&cntr[id], 1);
    } else {
        int id = hid[TBS + os[i]];
        os[i] = id;
        atomicAdd(&cntr[RB + id], 1);
    }
}

template<int D>
__global__ void build_neighbors(const unsigned long long* __restrict__ uk,
                                const unsigned long long* __restrict__ hk,
                                const int* __restrict__ hid,
                                int tmask, const int* cnt, int stride,
                                int* n1, int* n2) {
    int m = blockIdx.x * blockDim.x + threadIdx.x;
    if (m >= *cnt) return;
    unsigned long long k = uk[m];
    int c[D];
    #pragma unroll
    for (int i = 0; i < D; i++) c[i] = (int)((k >> (12 * i)) & 0xFFFULL) - 2048;
    for (int j = 0; j <= D; j++) {
        unsigned long long p1 = 0, p2 = 0;
        #pragma unroll
        for (int i = 0; i < D; i++) {
            int a = c[i] + ((i == j) ? D : -1);
            int b = c[i] + ((i == j) ? -D : 1);
            p1 |= ((unsigned long long)((unsigned)(a + 2048) & 0xFFFu)) << (12 * i);
            p2 |= ((unsigned long long)((unsigned)(b + 2048) & 0xFFFu)) << (12 * i);
        }
        n1[j * stride + m] = hash_lookup(hk, hid, tmask, p1);
        n2[j * stride + m] = hash_lookup(hk, hid, tmask, p2);
    }
}

// unified fill: epw is one packed-4B array, offsets global over RB+RS entries
__global__ void fill_both(const int* __restrict__ os, const float* __restrict__ wsv,
                          const int* __restrict__ off, int* fill, unsigned* epw) {
    int idx = blockIdx.x * blockDim.x + threadIdx.x;
    if (idx >= RB + RS) return;
    int slot, pix;
    if (idx < RB) { slot = os[idx];        pix = idx / DB1; }
    else          { slot = RB + os[idx];   pix = (idx - RB) / DS1; }
    int pos = off[slot] + atomicAdd(&fill[slot], 1);
    epw[pos] = pack_ew(pix, wsv[idx]);
}

// ---------------- batched filter kernels (fp16 storage, fp32 math) ----------------
__global__ void gather_both_h(const uint2* __restrict__ Qh, const int* __restrict__ off,
                              const int* __restrict__ cntr, const unsigned* __restrict__ epw,
                              uint2* __restrict__ buf, const int* cnt) {
    int Mb = cnt[0], Ms = cnt[1];
    int totB = (Mb + 1) * CP4;
    int tot = totB + (Ms + 1) * CP4;
    int stride = gridDim.x * blockDim.x;
    for (int idx = blockIdx.x * blockDim.x + threadIdx.x; idx < tot; idx += stride) {
        int c4, o, slot;
        if (idx < totB) {
            int row = idx / CP4; c4 = idx - row * CP4;
            o = idx;
            slot = row ? (row - 1) : -1;
        } else {
            int t = idx - totB;
            int row = t / CP4; c4 = t - row * CP4;
            o = (RB + 1 + row) * CP4 + c4;
            slot = row ? (RB + row - 1) : -1;
        }
        float4 acc = make_float4(0.f, 0.f, 0.f, 0.f);
        if (slot >= 0) {
            int s = off[slot], e = s + cntr[slot];
            for (int t = s; t < e; t++) {
                int pix; float w;
                unpack_ew(epw[t], pix, w);
                float4 v = u2f(Qh[(size_t)pix * CP4 + c4]);
                acc.x += w * v.x; acc.y += w * v.y; acc.z += w * v.z; acc.w += w * v.w;
            }
        }
        buf[o] = f2u(acc);
    }
}

__global__ void blur_both_h(const uint2* __restrict__ in, uint2* __restrict__ out,
                            const int* __restrict__ n1b, const int* __restrict__ n2b,
                            const int* __restrict__ n1s, const int* __restrict__ n2s,
                            const int* cnt) {
    int Mb = cnt[0], Ms = cnt[1];
    int totB = (Mb + 1) * CP4;
    int tot = totB + (Ms + 1) * CP4;
    int stride = gridDim.x * blockDim.x;
    for (int idx = blockIdx.x * blockDim.x + threadIdx.x; idx < tot; idx += stride) {
        if (idx < totB) {
            int row = idx / CP4, c4 = idx - row * CP4;
            if (row == 0) { out[idx] = make_uint2(0u, 0u); continue; }
            int m = row - 1;
            float4 a = u2f(in[(size_t)(n1b[m] + 1) * CP4 + c4]);
            float4 b = u2f(in[(size_t)(n2b[m] + 1) * CP4 + c4]);
            float4 x = u2f(in[idx]);
            x.x += 0.5f * (a.x + b.x); x.y += 0.5f * (a.y + b.y);
            x.z += 0.5f * (a.z + b.z); x.w += 0.5f * (a.w + b.w);
            out[idx] = f2u(x);
        } else {
            int t = idx - totB;
            int row = t / CP4, c4 = t - row * CP4;
            int o = (RB + 1 + row) * CP4 + c4;
            if (row == 0) { out[o] = make_uint2(0u, 0u); continue; }
            int m = row - 1;
            float4 a = u2f(in[(size_t)(RB + 2 + n1s[m]) * CP4 + c4]);  // -1 -> sink RB+1
            float4 b = u2f(in[(size_t)(RB + 2 + n2s[m]) * CP4 + c4]);
            float4 x = u2f(in[o]);
            x.x += 0.5f * (a.x + b.x); x.y += 0.5f * (a.y + b.y);
            x.z += 0.5f * (a.z + b.z); x.w += 0.5f * (a.w + b.w);
            out[o] = f2u(x);
        }
    }
}

__global__ void blur_b_h(const uint2* __restrict__ in, uint2* __restrict__ out,
                         const int* __restrict__ n1, const int* __restrict__ n2,
                         const int* cnt) {
    int M = cnt[0];
    int total = (M + 1) * CP4;
    int stride = gridDim.x * blockDim.x;
    for (int idx = blockIdx.x * blockDim.x + threadIdx.x; idx < total; idx += stride) {
        int row = idx / CP4, c4 = idx - row * CP4;
        if (row == 0) { out[idx] = make_uint2(0u, 0u); continue; }
        int m = row - 1;
        float4 a = u2f(in[(size_t)(n1[m] + 1) * CP4 + c4]);
        float4 b = u2f(in[(size_t)(n2[m] + 1) * CP4 + c4]);
        float4 x = u2f(in[idx]);
        x.x += 0.5f * (a.x + b.x); x.y += 0.5f * (a.y + b.y);
        x.z += 0.5f * (a.z + b.z); x.w += 0.5f * (a.w + b.w);
        out[idx] = f2u(x);
    }
}

// ---- fp32 norm-chain versions (per-row threads) ----
__global__ void gather1_both(const int* __restrict__ off, const int* __restrict__ cntr,
                             const unsigned* __restrict__ epw, float* __restrict__ buf,
                             const int* cnt) {
    int Mb = cnt[0], Ms = cnt[1];
    int totB = Mb + 1;
    int tot = totB + Ms + 1;
    int stride = gridDim.x * blockDim.x;
    for (int r = blockIdx.x * blockDim.x + threadIdx.x; r < tot; r += stride) {
        int o, slot;
        if (r < totB) { o = r;              slot = r ? (r - 1) : -1; }
        else          { int t = r - totB; o = RB + 1 + t; slot = t ? (RB + t - 1) : -1; }
        float acc = 0.f;
        if (slot >= 0) {
            int s = off[slot], e = s + cntr[slot];
            for (int t = s; t < e; t++) acc += (float)(epw[t] >> 17) * (1.0f / 32767.0f);
        }
        buf[o] = acc;
    }
}

__global__ void blur1_both(const float* __restrict__ in, float* __restrict__ out,
                           const int* __restrict__ n1b, const int* __restrict__ n2b,
                           const int* __restrict__ n1s, const int* __restrict__ n2s,
                           const int* cnt) {
    int Mb = cnt[0], Ms = cnt[1];
    int totB = Mb + 1;
    int tot = totB + Ms + 1;
    int stride = gridDim.x * blockDim.x;
    for (int r = blockIdx.x * blockDim.x + threadIdx.x; r < tot; r += stride) {
        if (r < totB) {
            if (r == 0) { out[0] = 0.f; continue; }
            int m = r - 1;
            out[r] = in[r] + 0.5f * (in[n1b[m] + 1] + in[n2b[m] + 1]);
        } else {
            int t = r - totB;
            int o = RB + 1 + t;
            if (t == 0) { out[o] = 0.f; continue; }
            int m = t - 1;
            out[o] = in[o] + 0.5f * (in[RB + 2 + n1s[m]] + in[RB + 2 + n2s[m]]);
        }
    }
}

__global__ void blur1_b(const float* __restrict__ in, float* __restrict__ out,
                        const int* __restrict__ n1, const int* __restrict__ n2,
                        const int* cnt) {
    int M = cnt[0];
    int stride = gridDim.x * blockDim.x;
    for (int row = blockIdx.x * blockDim.x + threadIdx.x; row <= M; row += stride) {
        if (row == 0) { out[0] = 0.f; continue; }
        int m = row - 1;
        out[row] = in[row] + 0.5f * (in[n1[m] + 1] + in[n2[m] + 1]);
    }
}

// both norms in one pass (bilateral final in bufB, spatial final in bufS)
__global__ void slice_norm_both(const float* __restrict__ bufB, const float* __restrict__ bufS,
                                const int* __restrict__ osw, const float* __restrict__ wsv,
                                float* __restrict__ nbv, float* __restrict__ nsv,
                                float alphaB, float alphaS) {
    int i = blockIdx.x * blockDim.x + threadIdx.x;
    if (i >= NPIX) return;
    float sb = 0.f;
    #pragma unroll
    for (int r = 0; r < DB1; r++)
        sb += wsv[i * DB1 + r] * bufB[osw[i * DB1 + r] + 1];
    float ss = 0.f;
    #pragma unroll
    for (int r = 0; r < DS1; r++)
        ss += wsv[RB + i * DS1 + r] * bufS[RB + 2 + osw[RB + i * DS1 + r]];
    nbv[i] = alphaB * sb + 1e-20f;
    nsv[i] = alphaS * ss + 1e-20f;
}

// fused: slice(bilateral)+slice(spatial)+normalize+softmax -> Q (fp32) + Qh (fp16)
__global__ void slice_update(const float* __restrict__ U,
                             const uint2* __restrict__ bufB, const uint2* __restrict__ bufS,
                             const int* __restrict__ osw, const float* __restrict__ wsv,
                             const float* __restrict__ nbv, const float* __restrict__ nsv,
                             float* __restrict__ Q, uint2* __restrict__ Qh,
                             float alphaB, float alphaS, int use_msg) {
    int i = blockIdx.x * blockDim.x + threadIdx.x;
    if (i >= NPIX) return;
    float msg[24];
    #pragma unroll
    for (int t = 0; t < 24; t++) msg[t] = 0.f;
    if (use_msg) {
        float ib = 10.0f * alphaB / nbv[i];
        float is = 3.0f * alphaS / nsv[i];
        #pragma unroll
        for (int r = 0; r < DB1; r++) {
            float w = ib * wsv[i * DB1 + r];
            size_t base = (size_t)(osw[i * DB1 + r] + 1) * CP4;
            #pragma unroll
            for (int t = 0; t < CP4; t++) {
                float4 v = u2f(bufB[base + t]);
                msg[4 * t + 0] += w * v.x; msg[4 * t + 1] += w * v.y;
                msg[4 * t + 2] += w * v.z; msg[4 * t + 3] += w * v.w;
            }
        }
        #pragma unroll
        for (int r = 0; r < DS1; r++) {
            float w = is * wsv[RB + i * DS1 + r];
            size_t base = (size_t)(RB + 2 + osw[RB + i * DS1 + r]) * CP4;
            #pragma unroll
            for (int t = 0; t < CP4; t++) {
                float4 v = u2f(bufS[base + t]);
                msg[4 * t + 0] += w * v.x; msg[4 * t + 1] += w * v.y;
                msg[4 * t + 2] += w * v.z; msg[4 * t + 3] += w * v.w;
            }
        }
    }
    float mx = -1e30f;
    #pragma unroll
    for (int c = 0; c < NC; c++) {
        msg[c] = -U[i * NC + c] + msg[c];
        mx = fmaxf(mx, msg[c]);
    }
    float s = 0.f;
    #pragma unroll
    for (int c = 0; c < NC; c++) { float e = expf(msg[c] - mx); msg[c] = e; s += e; }
    float inv = 1.0f / s;
    #pragma unroll
    for (int c = 0; c < NC; c++) {
        msg[c] *= inv;
        Q[i * NC + c] = msg[c];
    }
    msg[21] = 0.f; msg[22] = 0.f; msg[23] = 0.f;
    #pragma unroll
    for (int t = 0; t < CP4; t++)
        Qh[i * CP4 + t] = f2u(make_float4(msg[4 * t], msg[4 * t + 1], msg[4 * t + 2], msg[4 * t + 3]));
}

// ---------------- host orchestration ----------------
extern "C" void kernel_launch(void* const* d_in, const int* in_sizes, int n_in,
                              void* d_out, int out_size, void* d_ws, size_t ws_size,
                              hipStream_t stream) {
    const float* U     = (const float*)d_in[0];
    const float* image = (const float*)d_in[1];
    float* Q = (float*)d_out;

    char* base = (char*)d_ws;
    size_t off = 0;
    auto alloc = [&](size_t bytes) -> void* {
        off = (off + 255) & ~(size_t)255;
        void* p = base + off; off += bytes; return p;
    };
    // unified per-entry arrays: [0,RB) bilateral, [RB,RB+RS) spatial
    int*   osw  = (int*)  alloc((size_t)(RB + RS) * 4);
    float* wsv  = (float*)alloc((size_t)(RB + RS) * 4);
    int*   n1_b = (int*)  alloc((size_t)DB1 * RB * 4);
    int*   n2_b = (int*)  alloc((size_t)DB1 * RB * 4);
    int*   n1_s = (int*)  alloc((size_t)DS1 * RS * 4);
    int*   n2_s = (int*)  alloc((size_t)DS1 * RS * 4);
    unsigned long long* uk_b = (unsigned long long*)alloc((size_t)RB * 8);
    unsigned long long* uk_s = (unsigned long long*)alloc((size_t)RS * 8);
    unsigned long long* hk = (unsigned long long*)alloc((size_t)(TBS + TSS) * 8);
    int*   hid  = (int*)  alloc((size_t)(TBS + TSS) * 4);
    int*   cnt  = (int*)  alloc(256);   // [0]=M_b, [1]=M_s
    int*   histOff = (int*)alloc((size_t)2 * NBUCK * 4);
    int*   wsums   = (int*)alloc((size_t)64 * 1024 * 4);
    int*   wsI     = (int*)alloc((size_t)16384 * 4);   // level-1 inclusive sums
    int*   ws2     = (int*)alloc((size_t)1024 * 4);    // level-2 sums
    int*   offv    = (int*)alloc((size_t)(RB + RS) * 4);
    // contiguous zero region: cntr | fill | hist | histFill
    char*  zreg  = (char*)alloc((size_t)(RB + RS) * 8 + (size_t)2 * NBUCK * 8);
    int*   cntr     = (int*)zreg;
    int*   fill     = cntr + (RB + RS);
    int*   hist     = fill + (RB + RS);
    int*   histFill = hist + 2 * NBUCK;
    size_t zbytes = (size_t)(RB + RS) * 8 + (size_t)2 * NBUCK * 8;
    unsigned* epw = (unsigned*)alloc((size_t)(RB + RS) * 4);   // packed 4B entries
    float* norm_b = (float*)alloc((size_t)NPIX * 4);
    float* norm_s = (float*)alloc((size_t)NPIX * 4);
    uint2* Qh   = (uint2*)alloc((size_t)NPIX * CP4 * 8);
    // combined lattice buffers: rows RB+RS+2 (bilateral [0,RB], spatial [RB+1,...])
    uint2* buf0 = (uint2*)alloc((size_t)(RB + RS + 2) * CP4 * 8);
    uint2* buf1 = (uint2*)alloc((size_t)(RB + RS + 2) * CP4 * 8);
    float* nbuf0 = (float*)alloc((size_t)(RB + RS + 2) * 4);
    float* nbuf1 = (float*)alloc((size_t)(RB + RS + 2) * 4);
    if (off > ws_size) return;

    const float ALPHA_B = (float)(1.0 / (1.0 + exp2(-(double)DB)));  // 32/33
    const float ALPHA_S = (float)(1.0 / (1.0 + exp2(-(double)DS)));  // 4/5

    constexpr int PG = 4096;

    // ---- 3 memsets ----
    hipMemsetAsync(cnt, 0, 16, stream);
    hipMemsetAsync(hk, 0xFF, (size_t)(TBS + TSS) * 8, stream);
    hipMemsetAsync(zreg, 0, zbytes, stream);

    // ---- build both lattices (histogram fused into insertion) ----
    build_both<<<(2 * NPIX + 255) / 256, 256, 0, stream>>>(image, hk, osw, wsv, hist);
    // compaction scans per table (ids start at 0 for each)
    scan_wave_partial<<<NBUCK / 256, 256, 0, stream>>>(hist, histOff, wsums, NBUCK);
    scan_partials_excl<<<1, 256, 0, stream>>>(wsums, NBUCK / 64, cnt + 0);
    scan_finalize<<<NBUCK / 256, 256, 0, stream>>>(histOff, hist, wsums, NBUCK);
    scan_wave_partial<<<NBUCK / 256, 256, 0, stream>>>(hist + NBUCK, histOff + NBUCK, wsums, NBUCK);
    scan_partials_excl<<<1, 256, 0, stream>>>(wsums, NBUCK / 64, cnt + 1);
    scan_finalize<<<NBUCK / 256, 256, 0, stream>>>(histOff + NBUCK, hist + NBUCK, wsums, NBUCK);
    assign_both<<<(TBS + TSS) / 256, 256, 0, stream>>>(hk, hid, histOff, histFill, uk_b, uk_s);
    os_count_both<<<(RB + RS) / 256, 256, 0, stream>>>(osw, hid, cntr);
    build_neighbors<DB><<<(RB + 255) / 256, 256, 0, stream>>>(uk_b, hk, hid, TBS - 1, cnt + 0, RB, n1_b, n2_b);
    build_neighbors<DS><<<(RS + 255) / 256, 256, 0, stream>>>(uk_s, hk + TBS, hid + TBS, TSS - 1, cnt + 1, RS, n1_s, n2_s);
    // unified offset scan over RB+RS id slots — hierarchical
    scan_wave_partial<<<(RB + RS) / 256, 256, 0, stream>>>(cntr, offv, wsums, RB + RS);
    scan_wave_partial<<<(NW1 + 255) / 256, 256, 0, stream>>>(wsums, wsI, ws2, NW1);
    scan_partials_excl<<<1, 256, 0, stream>>>(ws2, (NW1 + 63) / 64, nullptr);
    scan_finalize<<<(NW1 + 255) / 256, 256, 0, stream>>>(wsI, wsums, ws2, NW1);
    scan_finalize<<<(RB + RS) / 256, 256, 0, stream>>>(offv, cntr, wsI, RB + RS);
    fill_both<<<(RB + RS + 255) / 256, 256, 0, stream>>>(osw, wsv, offv, fill, epw);

    // ---- norm filters (C=1, fp32), batched ----
    {
        gather1_both<<<1024, 256, 0, stream>>>(offv, cntr, epw, nbuf0, cnt);
        float* a = nbuf0; float* b = nbuf1;
        for (int j = 0; j < DS1; j++) {   // j=0..2: both chains
            blur1_both<<<1024, 256, 0, stream>>>(a, b,
                n1_b + (size_t)j * RB, n2_b + (size_t)j * RB,
                n1_s + (size_t)j * RS, n2_s + (size_t)j * RS, cnt);
            float* t = a; a = b; b = t;
        }
        // j=3..5: bilateral only — writes only rows [0,Mb]; spatial final stays in nbuf1.
        for (int j = DS1; j < DB1; j++) {
            blur1_b<<<1024, 256, 0, stream>>>(a, b, n1_b + (size_t)j * RB, n2_b + (size_t)j * RB, cnt);
            float* t = a; a = b; b = t;
        }
        // bilateral final in nbuf0 (6 swaps), spatial final in nbuf1 (3 swaps)
        slice_norm_both<<<(NPIX + 255) / 256, 256, 0, stream>>>(
            nbuf0, nbuf1, osw, wsv, norm_b, norm_s, ALPHA_B, ALPHA_S);
    }

    // ---- Q0 = softmax(-U) ----
    slice_update<<<(NPIX + 255) / 256, 256, 0, stream>>>(
        U, buf0, buf1, osw, wsv, norm_b, norm_s, Q, Qh, ALPHA_B, ALPHA_S, 0);

    // ---- 5 mean-field iterations ----
    for (int it = 0; it < 5; it++) {
        gather_both_h<<<PG, 256, 0, stream>>>(Qh, offv, cntr, epw, buf0, cnt);
        uint2* a = buf0; uint2* b = buf1;
        for (int j = 0; j < DS1; j++) {   // j=0..2: both chains in one launch
            blur_both_h<<<PG, 256, 0, stream>>>(a, b,
                n1_b + (size_t)j * RB, n2_b + (size_t)j * RB,
                n1_s + (size_t)j * RS, n2_s + (size_t)j * RS, cnt);
            uint2* t = a; a = b; b = t;
        }
        for (int j = DS1; j < DB1; j++) { // j=3..5: bilateral only
            blur_b_h<<<PG, 256, 0, stream>>>(a, b, n1_b + (size_t)j * RB, n2_b + (size_t)j * RB, cnt);
            uint2* t = a; a = b; b = t;
        }
        // bilateral final in buf0, spatial final in buf1
        slice_update<<<(NPIX + 255) / 256, 256, 0, stream>>>(
            U, buf0, buf1, osw, wsv, norm_b, norm_s, Q, Qh, ALPHA_B, ALPHA_S, 1);
    }
}

// Round 14
// 967.477 us; speedup vs baseline: 1.0196x; 1.0196x over previous
//
#include <hip/hip_runtime.h>
#include <hip/hip_fp16.h>
#include <cmath>

// ---------------- problem constants ----------------
constexpr int IMH = 320, IMW = 320, NPIX = IMH * IMW, NC = 21;
constexpr int CP4 = 6;           // padded channels / 4  (24 values per row)
constexpr int DB = 5, DB1 = 6;   // bilateral lattice dim
constexpr int DS = 2, DS1 = 3;   // spatial lattice dim
constexpr int RB = NPIX * DB1;   // splat entries (bilateral) = 614400
constexpr int RS = NPIX * DS1;   // (spatial) = 307200
constexpr int TBS = 1 << 20;     // hash table slots (bilateral)
constexpr int TSS = 1 << 18;     // hash table slots (spatial)
constexpr int NBUCK = 1 << 16;   // spatial-sort buckets (c0,c1 low bytes)
constexpr int NW1 = (RB + RS) / 64;  // wave sums in the unified offset scan

// Combined lattice-value buffer layout (static partition):
//   bilateral: row 0 = sink, point m -> row m+1           (rows [0, RB])
//   spatial:   row RB+1 = sink, point m -> row RB+2+m     (rows [RB+1, ...])
// spatial neighbor n=-1 maps to RB+2+(-1) = RB+1 = sink automatically.

// epw entry packing (4B): low 17 bits = pixel index, high 15 bits = weight
// quantized to [0,32767] fixed point (abs err 3e-5 << fp16 chain rounding).

// NOTE (r12/r13 lessons): fusing the bucket histogram into the insert loop
// cost ~45us (atomicAdd in the hot CAS loop); test-before-CAS added FETCH
// without cutting CAS count (concurrent inserts mostly observe EMPTY).
// Plain CAS-first insert + separate hist_both pass is the measured optimum.

#define EMPTY_KEY 0xFFFFFFFFFFFFFFFFULL

__device__ __forceinline__ unsigned long long mix64(unsigned long long x) {
    x ^= x >> 33; x *= 0xff51afd7ed558ccdULL;
    x ^= x >> 33; x *= 0xc4ceb9fe1a85ec53ULL;
    x ^= x >> 33; return x;
}

// fp16 pack helpers: uint2 = 4 halves; math in fp32, storage fp16.
__device__ __forceinline__ float4 u2f(uint2 u) {
    __half2 a = *reinterpret_cast<__half2*>(&u.x);
    __half2 b = *reinterpret_cast<__half2*>(&u.y);
    float2 fa = __half22float2(a), fb = __half22float2(b);
    return make_float4(fa.x, fa.y, fb.x, fb.y);
}
__device__ __forceinline__ uint2 f2u(float4 v) {
    __half2 a = __floats2half2_rn(v.x, v.y);
    __half2 b = __floats2half2_rn(v.z, v.w);
    uint2 u;
    u.x = *reinterpret_cast<unsigned*>(&a);
    u.y = *reinterpret_cast<unsigned*>(&b);
    return u;
}

__device__ __forceinline__ unsigned pack_ew(int pix, float w) {
    int w15 = (int)lrintf(fminf(fmaxf(w, 0.f), 1.f) * 32767.f);
    return ((unsigned)w15 << 17) | (unsigned)pix;
}
__device__ __forceinline__ void unpack_ew(unsigned e, int& pix, float& w) {
    pix = (int)(e & 0x1FFFFu);
    w = (float)(e >> 17) * (1.0f / 32767.0f);
}

// ---------------- permutohedral embedding (matches reference op-for-op, f32) ----------------
template<int D>
__device__ void perm_embed(const float* f, float* bary, unsigned long long* pk) {
    constexpr int D1 = D + 1;
    float cf[D];
    #pragma unroll
    for (int i = 0; i < D; i++) {
        double s = sqrt(2.0 / 3.0) * (double)D1 / sqrt((double)((i + 1) * (i + 2)));
        cf[i] = f[i] * (float)s;
    }
    float csum[D];
    float acc = 0.f;
    #pragma unroll
    for (int i = D - 1; i >= 0; i--) { acc += cf[i]; csum[i] = acc; }
    float el[D1];
    el[0] = csum[0];
    #pragma unroll
    for (int i = 1; i < D; i++) el[i] = csum[i] - (float)i * cf[i - 1];
    el[D] = -(float)D * cf[D - 1];
    const float down = 1.0f / (float)D1;
    float rem0[D1]; int rank[D1]; int ssum = 0;
    #pragma unroll
    for (int i = 0; i < D1; i++) {
        float rd = rintf(el[i] * down);
        rem0[i] = rd * (float)D1;
        ssum += (int)rd;
    }
    float diff[D1];
    #pragma unroll
    for (int i = 0; i < D1; i++) diff[i] = el[i] - rem0[i];
    #pragma unroll
    for (int i = 0; i < D1; i++) {
        int r = 0;
        #pragma unroll
        for (int j = 0; j < D1; j++)
            r += (diff[j] > diff[i]) || ((diff[j] == diff[i]) && (j < i));
        rank[i] = r + ssum;
    }
    #pragma unroll
    for (int i = 0; i < D1; i++) {
        if (rank[i] < 0)      { rank[i] += D1; rem0[i] += (float)D1; }
        else if (rank[i] > D) { rank[i] -= D1; rem0[i] -= (float)D1; }
    }
    float b[D + 2];
    #pragma unroll
    for (int i = 0; i < D + 2; i++) b[i] = 0.f;
    #pragma unroll
    for (int i = 0; i < D1; i++) b[D - rank[i]]     += (el[i] - rem0[i]) * down;
    #pragma unroll
    for (int i = 0; i < D1; i++) b[D + 1 - rank[i]] -= (el[i] - rem0[i]) * down;
    b[0] += 1.0f + b[D + 1];
    #pragma unroll
    for (int i = 0; i < D1; i++) bary[i] = b[i];
    int key0[D];
    #pragma unroll
    for (int i = 0; i < D; i++) key0[i] = (int)rintf(rem0[i]);
    #pragma unroll
    for (int r = 0; r < D1; r++) {
        unsigned long long p = 0;
        #pragma unroll
        for (int i = 0; i < D; i++) {
            int c = key0[i] + ((rank[i] < D1 - r) ? r : r - D1);
            p |= ((unsigned long long)((unsigned)(c + 2048) & 0xFFFu)) << (12 * i);
        }
        pk[r] = p;
    }
}

__device__ __forceinline__ int key_code(unsigned long long k) {
    int c0 = (int)(k & 0xFFFULL);
    int c1 = (int)((k >> 12) & 0xFFFULL);
    return ((c0 & 0xFF) << 8) | (c1 & 0xFF);
}

// ---------------- hash table (r11-proven plain CAS-first insert) ----------------
__device__ __forceinline__ int hash_insert(unsigned long long* hk, int tmask, unsigned long long k) {
    int slot = (int)(mix64(k) & (unsigned long long)tmask);
    while (true) {
        unsigned long long prev = atomicCAS(&hk[slot], EMPTY_KEY, k);
        if (prev == EMPTY_KEY || prev == k) return slot;
        slot = (slot + 1) & tmask;
    }
}
__device__ __forceinline__ int hash_lookup(const unsigned long long* hk, const int* hid,
                                           int tmask, unsigned long long k) {
    int slot = (int)(mix64(k) & (unsigned long long)tmask);
    while (true) {
        unsigned long long v = hk[slot];
        if (v == k) return hid[slot];
        if (v == EMPTY_KEY) return -1;
        slot = (slot + 1) & tmask;
    }
}

// ---------------- build kernels ----------------
// one launch builds both lattices (hk = unified table: [0,TBS) bilateral, [TBS,+TSS) spatial)
__global__ void build_both(const float* __restrict__ image, unsigned long long* hk,
                           int* os, float* wsv) {
    int i = blockIdx.x * blockDim.x + threadIdx.x;
    if (i < NPIX) {
        int x = i % IMW, y = i / IMW;
        float f[DB];
        f[0] = (float)x / 80.0f;
        f[1] = (float)y / 80.0f;
        f[2] = image[i * 3 + 0] / 13.0f;
        f[3] = image[i * 3 + 1] / 13.0f;
        f[4] = image[i * 3 + 2] / 13.0f;
        float bary[DB1]; unsigned long long pk[DB1];
        perm_embed<DB>(f, bary, pk);
        #pragma unroll
        for (int r = 0; r < DB1; r++) {
            wsv[i * DB1 + r] = bary[r];
            os[i * DB1 + r] = hash_insert(hk, TBS - 1, pk[r]);
        }
    } else if (i < 2 * NPIX) {
        int ip = i - NPIX;
        int x = ip % IMW, y = ip / IMW;
        float f[DS];
        f[0] = (float)x / 3.0f;
        f[1] = (float)y / 3.0f;
        float bary[DS1]; unsigned long long pk[DS1];
        perm_embed<DS>(f, bary, pk);
        #pragma unroll
        for (int r = 0; r < DS1; r++) {
            wsv[RB + ip * DS1 + r] = bary[r];
            os[RB + ip * DS1 + r] = hash_insert(hk + TBS, TSS - 1, pk[r]);
        }
    }
}

// hist over BOTH tables in one pass (hist halves: [0,NBUCK) b, [NBUCK,2N) s)
__global__ void hist_both(const unsigned long long* __restrict__ hk, int* hist) {
    int s = blockIdx.x * blockDim.x + threadIdx.x;
    if (s >= TBS + TSS) return;
    unsigned long long k = hk[s];
    if (k == EMPTY_KEY) return;
    int half = (s < TBS) ? 0 : NBUCK;
    atomicAdd(&hist[half + key_code(k)], 1);
}

// ---------------- barrier-free scan machinery ----------------
__global__ void scan_wave_partial(const int* __restrict__ count, int* incl, int* wsum, int n) {
    int idx = blockIdx.x * blockDim.x + threadIdx.x;
    int lane = threadIdx.x & 63;
    int v = (idx < n) ? count[idx] : 0;
    int s = v;
    #pragma unroll
    for (int d = 1; d < 64; d <<= 1) {
        int t = __shfl_up(s, d);
        if (lane >= d) s += t;
    }
    if (idx < n) incl[idx] = s;
    if (lane == 63) wsum[idx >> 6] = s;
}

__global__ void scan_partials_excl(int* w, int nw, int* total_out) {
    __shared__ int sh[256];
    __shared__ int run;
    if (threadIdx.x == 0) run = 0;
    __syncthreads();
    for (int basei = 0; basei < nw; basei += 256) {
        int idx = basei + threadIdx.x;
        int v = (idx < nw) ? w[idx] : 0;
        sh[threadIdx.x] = v;
        __syncthreads();
        for (int d = 1; d < 256; d <<= 1) {
            int t = (threadIdx.x >= d) ? sh[threadIdx.x - d] : 0;
            __syncthreads();
            sh[threadIdx.x] += t;
            __syncthreads();
        }
        int total = sh[255];
        if (idx < nw) w[idx] = run + sh[threadIdx.x] - v;
        __syncthreads();
        if (threadIdx.x == 0) run += total;
        __syncthreads();
    }
    if (total_out != nullptr && threadIdx.x == 0) *total_out = run;
}

__global__ void scan_finalize(int* off, const int* __restrict__ count,
                              const int* __restrict__ wsum, int n) {
    int idx = blockIdx.x * blockDim.x + threadIdx.x;
    if (idx < n) off[idx] = off[idx] - count[idx] + wsum[idx >> 6];
}

// ---------------- bucket-sorted compaction ----------------
__global__ void assign_both(const unsigned long long* __restrict__ hk, int* hid,
                            const int* __restrict__ histOff, int* histFill,
                            unsigned long long* uk_b, unsigned long long* uk_s) {
    int s = blockIdx.x * blockDim.x + threadIdx.x;
    if (s >= TBS + TSS) return;
    unsigned long long k = hk[s];
    if (k == EMPTY_KEY) return;
    int half = (s < TBS) ? 0 : NBUCK;
    int code = half + key_code(k);
    int id = histOff[code] + atomicAdd(&histFill[code], 1);
    hid[s] = id;
    if (s < TBS) uk_b[id] = k; else uk_s[id] = k;
}

// unified os remap + cntr histogram (cntr slots: [0,RB) bilateral ids, [RB,RB+RS) spatial)
__global__ void os_count_both(int* os, const int* __restrict__ hid, int* cntr) {
    int i = blockIdx.x * blockDim.x + threadIdx.x;
    if (i >= RB + RS) return;
    if (i < RB) {
        int id = hid[os[i]];
        os[i] = id;
        atomicAdd(&cntr[id], 1);
    } else {
        int id = hid[TBS + os[i]];
        os[i] = id;
        atomicAdd(&cntr[RB + id], 1);
    }
}

template<int D>
__global__ void build_neighbors(const unsigned long long* __restrict__ uk,
                                const unsigned long long* __restrict__ hk,
                                const int* __restrict__ hid,
                                int tmask, const int* cnt, int stride,
                                int* n1, int* n2) {
    int m = blockIdx.x * blockDim.x + threadIdx.x;
    if (m >= *cnt) return;
    unsigned long long k = uk[m];
    int c[D];
    #pragma unroll
    for (int i = 0; i < D; i++) c[i] = (int)((k >> (12 * i)) & 0xFFFULL) - 2048;
    for (int j = 0; j <= D; j++) {
        unsigned long long p1 = 0, p2 = 0;
        #pragma unroll
        for (int i = 0; i < D; i++) {
            int a = c[i] + ((i == j) ? D : -1);
            int b = c[i] + ((i == j) ? -D : 1);
            p1 |= ((unsigned long long)((unsigned)(a + 2048) & 0xFFFu)) << (12 * i);
            p2 |= ((unsigned long long)((unsigned)(b + 2048) & 0xFFFu)) << (12 * i);
        }
        n1[j * stride + m] = hash_lookup(hk, hid, tmask, p1);
        n2[j * stride + m] = hash_lookup(hk, hid, tmask, p2);
    }
}

// unified fill: epw is one packed-4B array, offsets global over RB+RS entries
__global__ void fill_both(const int* __restrict__ os, const float* __restrict__ wsv,
                          const int* __restrict__ off, int* fill, unsigned* epw) {
    int idx = blockIdx.x * blockDim.x + threadIdx.x;
    if (idx >= RB + RS) return;
    int slot, pix;
    if (idx < RB) { slot = os[idx];        pix = idx / DB1; }
    else          { slot = RB + os[idx];   pix = (idx - RB) / DS1; }
    int pos = off[slot] + atomicAdd(&fill[slot], 1);
    epw[pos] = pack_ew(pix, wsv[idx]);
}

// ---------------- batched filter kernels (fp16 storage, fp32 math) ----------------
__global__ void gather_both_h(const uint2* __restrict__ Qh, const int* __restrict__ off,
                              const int* __restrict__ cntr, const unsigned* __restrict__ epw,
                              uint2* __restrict__ buf, const int* cnt) {
    int Mb = cnt[0], Ms = cnt[1];
    int totB = (Mb + 1) * CP4;
    int tot = totB + (Ms + 1) * CP4;
    int stride = gridDim.x * blockDim.x;
    for (int idx = blockIdx.x * blockDim.x + threadIdx.x; idx < tot; idx += stride) {
        int c4, o, slot;
        if (idx < totB) {
            int row = idx / CP4; c4 = idx - row * CP4;
            o = idx;
            slot = row ? (row - 1) : -1;
        } else {
            int t = idx - totB;
            int row = t / CP4; c4 = t - row * CP4;
            o = (RB + 1 + row) * CP4 + c4;
            slot = row ? (RB + row - 1) : -1;
        }
        float4 acc = make_float4(0.f, 0.f, 0.f, 0.f);
        if (slot >= 0) {
            int s = off[slot], e = s + cntr[slot];
            for (int t = s; t < e; t++) {
                int pix; float w;
                unpack_ew(epw[t], pix, w);
                float4 v = u2f(Qh[(size_t)pix * CP4 + c4]);
                acc.x += w * v.x; acc.y += w * v.y; acc.z += w * v.z; acc.w += w * v.w;
            }
        }
        buf[o] = f2u(acc);
    }
}

__global__ void blur_both_h(const uint2* __restrict__ in, uint2* __restrict__ out,
                            const int* __restrict__ n1b, const int* __restrict__ n2b,
                            const int* __restrict__ n1s, const int* __restrict__ n2s,
                            const int* cnt) {
    int Mb = cnt[0], Ms = cnt[1];
    int totB = (Mb + 1) * CP4;
    int tot = totB + (Ms + 1) * CP4;
    int stride = gridDim.x * blockDim.x;
    for (int idx = blockIdx.x * blockDim.x + threadIdx.x; idx < tot; idx += stride) {
        if (idx < totB) {
            int row = idx / CP4, c4 = idx - row * CP4;
            if (row == 0) { out[idx] = make_uint2(0u, 0u); continue; }
            int m = row - 1;
            float4 a = u2f(in[(size_t)(n1b[m] + 1) * CP4 + c4]);
            float4 b = u2f(in[(size_t)(n2b[m] + 1) * CP4 + c4]);
            float4 x = u2f(in[idx]);
            x.x += 0.5f * (a.x + b.x); x.y += 0.5f * (a.y + b.y);
            x.z += 0.5f * (a.z + b.z); x.w += 0.5f * (a.w + b.w);
            out[idx] = f2u(x);
        } else {
            int t = idx - totB;
            int row = t / CP4, c4 = t - row * CP4;
            int o = (RB + 1 + row) * CP4 + c4;
            if (row == 0) { out[o] = make_uint2(0u, 0u); continue; }
            int m = row - 1;
            float4 a = u2f(in[(size_t)(RB + 2 + n1s[m]) * CP4 + c4]);  // -1 -> sink RB+1
            float4 b = u2f(in[(size_t)(RB + 2 + n2s[m]) * CP4 + c4]);
            float4 x = u2f(in[o]);
            x.x += 0.5f * (a.x + b.x); x.y += 0.5f * (a.y + b.y);
            x.z += 0.5f * (a.z + b.z); x.w += 0.5f * (a.w + b.w);
            out[o] = f2u(x);
        }
    }
}

__global__ void blur_b_h(const uint2* __restrict__ in, uint2* __restrict__ out,
                         const int* __restrict__ n1, const int* __restrict__ n2,
                         const int* cnt) {
    int M = cnt[0];
    int total = (M + 1) * CP4;
    int stride = gridDim.x * blockDim.x;
    for (int idx = blockIdx.x * blockDim.x + threadIdx.x; idx < total; idx += stride) {
        int row = idx / CP4, c4 = idx - row * CP4;
        if (row == 0) { out[idx] = make_uint2(0u, 0u); continue; }
        int m = row - 1;
        float4 a = u2f(in[(size_t)(n1[m] + 1) * CP4 + c4]);
        float4 b = u2f(in[(size_t)(n2[m] + 1) * CP4 + c4]);
        float4 x = u2f(in[idx]);
        x.x += 0.5f * (a.x + b.x); x.y += 0.5f * (a.y + b.y);
        x.z += 0.5f * (a.z + b.z); x.w += 0.5f * (a.w + b.w);
        out[idx] = f2u(x);
    }
}

// ---- fp32 norm-chain versions (per-row threads) ----
__global__ void gather1_both(const int* __restrict__ off, const int* __restrict__ cntr,
                             const unsigned* __restrict__ epw, float* __restrict__ buf,
                             const int* cnt) {
    int Mb = cnt[0], Ms = cnt[1];
    int totB = Mb + 1;
    int tot = totB + Ms + 1;
    int stride = gridDim.x * blockDim.x;
    for (int r = blockIdx.x * blockDim.x + threadIdx.x; r < tot; r += stride) {
        int o, slot;
        if (r < totB) { o = r;              slot = r ? (r - 1) : -1; }
        else          { int t = r - totB; o = RB + 1 + t; slot = t ? (RB + t - 1) : -1; }
        float acc = 0.f;
        if (slot >= 0) {
            int s = off[slot], e = s + cntr[slot];
            for (int t = s; t < e; t++) acc += (float)(epw[t] >> 17) * (1.0f / 32767.0f);
        }
        buf[o] = acc;
    }
}

__global__ void blur1_both(const float* __restrict__ in, float* __restrict__ out,
                           const int* __restrict__ n1b, const int* __restrict__ n2b,
                           const int* __restrict__ n1s, const int* __restrict__ n2s,
                           const int* cnt) {
    int Mb = cnt[0], Ms = cnt[1];
    int totB = Mb + 1;
    int tot = totB + Ms + 1;
    int stride = gridDim.x * blockDim.x;
    for (int r = blockIdx.x * blockDim.x + threadIdx.x; r < tot; r += stride) {
        if (r < totB) {
            if (r == 0) { out[0] = 0.f; continue; }
            int m = r - 1;
            out[r] = in[r] + 0.5f * (in[n1b[m] + 1] + in[n2b[m] + 1]);
        } else {
            int t = r - totB;
            int o = RB + 1 + t;
            if (t == 0) { out[o] = 0.f; continue; }
            int m = t - 1;
            out[o] = in[o] + 0.5f * (in[RB + 2 + n1s[m]] + in[RB + 2 + n2s[m]]);
        }
    }
}

__global__ void blur1_b(const float* __restrict__ in, float* __restrict__ out,
                        const int* __restrict__ n1, const int* __restrict__ n2,
                        const int* cnt) {
    int M = cnt[0];
    int stride = gridDim.x * blockDim.x;
    for (int row = blockIdx.x * blockDim.x + threadIdx.x; row <= M; row += stride) {
        if (row == 0) { out[0] = 0.f; continue; }
        int m = row - 1;
        out[row] = in[row] + 0.5f * (in[n1[m] + 1] + in[n2[m] + 1]);
    }
}

// both norms in one pass (bilateral final in bufB, spatial final in bufS)
__global__ void slice_norm_both(const float* __restrict__ bufB, const float* __restrict__ bufS,
                                const int* __restrict__ osw, const float* __restrict__ wsv,
                                float* __restrict__ nbv, float* __restrict__ nsv,
                                float alphaB, float alphaS) {
    int i = blockIdx.x * blockDim.x + threadIdx.x;
    if (i >= NPIX) return;
    float sb = 0.f;
    #pragma unroll
    for (int r = 0; r < DB1; r++)
        sb += wsv[i * DB1 + r] * bufB[osw[i * DB1 + r] + 1];
    float ss = 0.f;
    #pragma unroll
    for (int r = 0; r < DS1; r++)
        ss += wsv[RB + i * DS1 + r] * bufS[RB + 2 + osw[RB + i * DS1 + r]];
    nbv[i] = alphaB * sb + 1e-20f;
    nsv[i] = alphaS * ss + 1e-20f;
}

// fused: slice(bilateral)+slice(spatial)+normalize+softmax -> Q (fp32) + Qh (fp16)
__global__ void slice_update(const float* __restrict__ U,
                             const uint2* __restrict__ bufB, const uint2* __restrict__ bufS,
                             const int* __restrict__ osw, const float* __restrict__ wsv,
                             const float* __restrict__ nbv, const float* __restrict__ nsv,
                             float* __restrict__ Q, uint2* __restrict__ Qh,
                             float alphaB, float alphaS, int use_msg) {
    int i = blockIdx.x * blockDim.x + threadIdx.x;
    if (i >= NPIX) return;
    float msg[24];
    #pragma unroll
    for (int t = 0; t < 24; t++) msg[t] = 0.f;
    if (use_msg) {
        float ib = 10.0f * alphaB / nbv[i];
        float is = 3.0f * alphaS / nsv[i];
        #pragma unroll
        for (int r = 0; r < DB1; r++) {
            float w = ib * wsv[i * DB1 + r];
            size_t base = (size_t)(osw[i * DB1 + r] + 1) * CP4;
            #pragma unroll
            for (int t = 0; t < CP4; t++) {
                float4 v = u2f(bufB[base + t]);
                msg[4 * t + 0] += w * v.x; msg[4 * t + 1] += w * v.y;
                msg[4 * t + 2] += w * v.z; msg[4 * t + 3] += w * v.w;
            }
        }
        #pragma unroll
        for (int r = 0; r < DS1; r++) {
            float w = is * wsv[RB + i * DS1 + r];
            size_t base = (size_t)(RB + 2 + osw[RB + i * DS1 + r]) * CP4;
            #pragma unroll
            for (int t = 0; t < CP4; t++) {
                float4 v = u2f(bufS[base + t]);
                msg[4 * t + 0] += w * v.x; msg[4 * t + 1] += w * v.y;
                msg[4 * t + 2] += w * v.z; msg[4 * t + 3] += w * v.w;
            }
        }
    }
    float mx = -1e30f;
    #pragma unroll
    for (int c = 0; c < NC; c++) {
        msg[c] = -U[i * NC + c] + msg[c];
        mx = fmaxf(mx, msg[c]);
    }
    float s = 0.f;
    #pragma unroll
    for (int c = 0; c < NC; c++) { float e = expf(msg[c] - mx); msg[c] = e; s += e; }
    float inv = 1.0f / s;
    #pragma unroll
    for (int c = 0; c < NC; c++) {
        msg[c] *= inv;
        Q[i * NC + c] = msg[c];
    }
    msg[21] = 0.f; msg[22] = 0.f; msg[23] = 0.f;
    #pragma unroll
    for (int t = 0; t < CP4; t++)
        Qh[i * CP4 + t] = f2u(make_float4(msg[4 * t], msg[4 * t + 1], msg[4 * t + 2], msg[4 * t + 3]));
}

// ---------------- host orchestration ----------------
extern "C" void kernel_launch(void* const* d_in, const int* in_sizes, int n_in,
                              void* d_out, int out_size, void* d_ws, size_t ws_size,
                              hipStream_t stream) {
    const float* U     = (const float*)d_in[0];
    const float* image = (const float*)d_in[1];
    float* Q = (float*)d_out;

    char* base = (char*)d_ws;
    size_t off = 0;
    auto alloc = [&](size_t bytes) -> void* {
        off = (off + 255) & ~(size_t)255;
        void* p = base + off; off += bytes; return p;
    };
    // unified per-entry arrays: [0,RB) bilateral, [RB,RB+RS) spatial
    int*   osw  = (int*)  alloc((size_t)(RB + RS) * 4);
    float* wsv  = (float*)alloc((size_t)(RB + RS) * 4);
    int*   n1_b = (int*)  alloc((size_t)DB1 * RB * 4);
    int*   n2_b = (int*)  alloc((size_t)DB1 * RB * 4);
    int*   n1_s = (int*)  alloc((size_t)DS1 * RS * 4);
    int*   n2_s = (int*)  alloc((size_t)DS1 * RS * 4);
    unsigned long long* uk_b = (unsigned long long*)alloc((size_t)RB * 8);
    unsigned long long* uk_s = (unsigned long long*)alloc((size_t)RS * 8);
    unsigned long long* hk = (unsigned long long*)alloc((size_t)(TBS + TSS) * 8);
    int*   hid  = (int*)  alloc((size_t)(TBS + TSS) * 4);
    int*   cnt  = (int*)  alloc(256);   // [0]=M_b, [1]=M_s
    int*   histOff = (int*)alloc((size_t)2 * NBUCK * 4);
    int*   wsums   = (int*)alloc((size_t)64 * 1024 * 4);
    int*   wsI     = (int*)alloc((size_t)16384 * 4);   // level-1 inclusive sums
    int*   ws2     = (int*)alloc((size_t)1024 * 4);    // level-2 sums
    int*   offv    = (int*)alloc((size_t)(RB + RS) * 4);
    // contiguous zero region: cntr | fill | hist | histFill
    char*  zreg  = (char*)alloc((size_t)(RB + RS) * 8 + (size_t)2 * NBUCK * 8);
    int*   cntr     = (int*)zreg;
    int*   fill     = cntr + (RB + RS);
    int*   hist     = fill + (RB + RS);
    int*   histFill = hist + 2 * NBUCK;
    size_t zbytes = (size_t)(RB + RS) * 8 + (size_t)2 * NBUCK * 8;
    unsigned* epw = (unsigned*)alloc((size_t)(RB + RS) * 4);   // packed 4B entries
    float* norm_b = (float*)alloc((size_t)NPIX * 4);
    float* norm_s = (float*)alloc((size_t)NPIX * 4);
    uint2* Qh   = (uint2*)alloc((size_t)NPIX * CP4 * 8);
    // combined lattice buffers: rows RB+RS+2 (bilateral [0,RB], spatial [RB+1,...])
    uint2* buf0 = (uint2*)alloc((size_t)(RB + RS + 2) * CP4 * 8);
    uint2* buf1 = (uint2*)alloc((size_t)(RB + RS + 2) * CP4 * 8);
    float* nbuf0 = (float*)alloc((size_t)(RB + RS + 2) * 4);
    float* nbuf1 = (float*)alloc((size_t)(RB + RS + 2) * 4);
    if (off > ws_size) return;

    const float ALPHA_B = (float)(1.0 / (1.0 + exp2(-(double)DB)));  // 32/33
    const float ALPHA_S = (float)(1.0 / (1.0 + exp2(-(double)DS)));  // 4/5

    constexpr int PG = 4096;

    // ---- 3 memsets ----
    hipMemsetAsync(cnt, 0, 16, stream);
    hipMemsetAsync(hk, 0xFF, (size_t)(TBS + TSS) * 8, stream);
    hipMemsetAsync(zreg, 0, zbytes, stream);

    // ---- build both lattices ----
    build_both<<<(2 * NPIX + 255) / 256, 256, 0, stream>>>(image, hk, osw, wsv);
    hist_both<<<(TBS + TSS) / 256, 256, 0, stream>>>(hk, hist);
    // compaction scans per table (ids start at 0 for each)
    scan_wave_partial<<<NBUCK / 256, 256, 0, stream>>>(hist, histOff, wsums, NBUCK);
    scan_partials_excl<<<1, 256, 0, stream>>>(wsums, NBUCK / 64, cnt + 0);
    scan_finalize<<<NBUCK / 256, 256, 0, stream>>>(histOff, hist, wsums, NBUCK);
    scan_wave_partial<<<NBUCK / 256, 256, 0, stream>>>(hist + NBUCK, histOff + NBUCK, wsums, NBUCK);
    scan_partials_excl<<<1, 256, 0, stream>>>(wsums, NBUCK / 64, cnt + 1);
    scan_finalize<<<NBUCK / 256, 256, 0, stream>>>(histOff + NBUCK, hist + NBUCK, wsums, NBUCK);
    assign_both<<<(TBS + TSS) / 256, 256, 0, stream>>>(hk, hid, histOff, histFill, uk_b, uk_s);
    os_count_both<<<(RB + RS) / 256, 256, 0, stream>>>(osw, hid, cntr);
    build_neighbors<DB><<<(RB + 255) / 256, 256, 0, stream>>>(uk_b, hk, hid, TBS - 1, cnt + 0, RB, n1_b, n2_b);
    build_neighbors<DS><<<(RS + 255) / 256, 256, 0, stream>>>(uk_s, hk + TBS, hid + TBS, TSS - 1, cnt + 1, RS, n1_s, n2_s);
    // unified offset scan over RB+RS id slots — hierarchical
    scan_wave_partial<<<(RB + RS) / 256, 256, 0, stream>>>(cntr, offv, wsums, RB + RS);
    scan_wave_partial<<<(NW1 + 255) / 256, 256, 0, stream>>>(wsums, wsI, ws2, NW1);
    scan_partials_excl<<<1, 256, 0, stream>>>(ws2, (NW1 + 63) / 64, nullptr);
    scan_finalize<<<(NW1 + 255) / 256, 256, 0, stream>>>(wsI, wsums, ws2, NW1);
    scan_finalize<<<(RB + RS) / 256, 256, 0, stream>>>(offv, cntr, wsI, RB + RS);
    fill_both<<<(RB + RS + 255) / 256, 256, 0, stream>>>(osw, wsv, offv, fill, epw);

    // ---- norm filters (C=1, fp32), batched ----
    {
        gather1_both<<<1024, 256, 0, stream>>>(offv, cntr, epw, nbuf0, cnt);
        float* a = nbuf0; float* b = nbuf1;
        for (int j = 0; j < DS1; j++) {   // j=0..2: both chains
            blur1_both<<<1024, 256, 0, stream>>>(a, b,
                n1_b + (size_t)j * RB, n2_b + (size_t)j * RB,
                n1_s + (size_t)j * RS, n2_s + (size_t)j * RS, cnt);
            float* t = a; a = b; b = t;
        }
        // j=3..5: bilateral only — writes only rows [0,Mb]; spatial final stays in nbuf1.
        for (int j = DS1; j < DB1; j++) {
            blur1_b<<<1024, 256, 0, stream>>>(a, b, n1_b + (size_t)j * RB, n2_b + (size_t)j * RB, cnt);
            float* t = a; a = b; b = t;
        }
        // bilateral final in nbuf0 (6 swaps), spatial final in nbuf1 (3 swaps)
        slice_norm_both<<<(NPIX + 255) / 256, 256, 0, stream>>>(
            nbuf0, nbuf1, osw, wsv, norm_b, norm_s, ALPHA_B, ALPHA_S);
    }

    // ---- Q0 = softmax(-U) ----
    slice_update<<<(NPIX + 255) / 256, 256, 0, stream>>>(
        U, buf0, buf1, osw, wsv, norm_b, norm_s, Q, Qh, ALPHA_B, ALPHA_S, 0);

    // ---- 5 mean-field iterations ----
    for (int it = 0; it < 5; it++) {
        gather_both_h<<<PG, 256, 0, stream>>>(Qh, offv, cntr, epw, buf0, cnt);
        uint2* a = buf0; uint2* b = buf1;
        for (int j = 0; j < DS1; j++) {   // j=0..2: both chains in one launch
            blur_both_h<<<PG, 256, 0, stream>>>(a, b,
                n1_b + (size_t)j * RB, n2_b + (size_t)j * RB,
                n1_s + (size_t)j * RS, n2_s + (size_t)j * RS, cnt);
            uint2* t = a; a = b; b = t;
        }
        for (int j = DS1; j < DB1; j++) { // j=3..5: bilateral only
            blur_b_h<<<PG, 256, 0, stream>>>(a, b, n1_b + (size_t)j * RB, n2_b + (size_t)j * RB, cnt);
            uint2* t = a; a = b; b = t;
        }
        // bilateral final in buf0, spatial final in buf1
        slice_update<<<(NPIX + 255) / 256, 256, 0, stream>>>(
            U, buf0, buf1, osw, wsv, norm_b, norm_s, Q, Qh, ALPHA_B, ALPHA_S, 1);
    }
}

// Round 15
// 926.196 us; speedup vs baseline: 1.0651x; 1.0446x over previous
//
#include <hip/hip_runtime.h>
#include <hip/hip_fp16.h>
#include <cmath>

// ---------------- problem constants ----------------
constexpr int IMH = 320, IMW = 320, NPIX = IMH * IMW, NC = 21;
constexpr int CP4 = 6;           // padded channels / 4  (24 values per row)
constexpr int DB = 5, DB1 = 6;   // bilateral lattice dim
constexpr int DS = 2, DS1 = 3;   // spatial lattice dim
constexpr int RB = NPIX * DB1;   // splat entries (bilateral) = 614400
constexpr int RS = NPIX * DS1;   // (spatial) = 307200
constexpr int TBS = 1 << 19;     // hash table slots (bilateral; load ~0.33)
constexpr int TSS = 1 << 18;     // hash table slots (spatial)
constexpr int NBUCK = 1 << 16;   // spatial-sort buckets (c0,c1 low bytes)
constexpr int NW1 = (RB + RS) / 64;  // wave sums in the unified offset scan

// Combined lattice-value buffer layout (static partition):
//   bilateral: row 0 = sink, point m -> row m+1           (rows [0, RB])
//   spatial:   row RB+1 = sink, point m -> row RB+2+m     (rows [RB+1, ...])
// spatial neighbor n=-1 maps to RB+2+(-1) = RB+1 = sink automatically.

// epw entry packing (4B): low 17 bits = pixel index, high 15 bits = weight
// quantized to [0,32767] fixed point (abs err 3e-5 << fp16 chain rounding).

// LESSONS (r12-r14, measured): hist fused into the CAS loop = +45us; test-
// before-CAS = +8us and +36MB FETCH (concurrent inserts observe EMPTY anyway);
// 4B epw packing does NOT cut scatter WRITE (64B sector granularity rules).
// r15: fill's atomicAdd removed via ranks captured in os_count (free from its
// existing atomicAdd return value) — kills ~921K scattered RMWs.

#define EMPTY_KEY 0xFFFFFFFFFFFFFFFFULL

__device__ __forceinline__ unsigned long long mix64(unsigned long long x) {
    x ^= x >> 33; x *= 0xff51afd7ed558ccdULL;
    x ^= x >> 33; x *= 0xc4ceb9fe1a85ec53ULL;
    x ^= x >> 33; return x;
}

// fp16 pack helpers: uint2 = 4 halves; math in fp32, storage fp16.
__device__ __forceinline__ float4 u2f(uint2 u) {
    __half2 a = *reinterpret_cast<__half2*>(&u.x);
    __half2 b = *reinterpret_cast<__half2*>(&u.y);
    float2 fa = __half22float2(a), fb = __half22float2(b);
    return make_float4(fa.x, fa.y, fb.x, fb.y);
}
__device__ __forceinline__ uint2 f2u(float4 v) {
    __half2 a = __floats2half2_rn(v.x, v.y);
    __half2 b = __floats2half2_rn(v.z, v.w);
    uint2 u;
    u.x = *reinterpret_cast<unsigned*>(&a);
    u.y = *reinterpret_cast<unsigned*>(&b);
    return u;
}

__device__ __forceinline__ unsigned pack_ew(int pix, float w) {
    int w15 = (int)lrintf(fminf(fmaxf(w, 0.f), 1.f) * 32767.f);
    return ((unsigned)w15 << 17) | (unsigned)pix;
}
__device__ __forceinline__ void unpack_ew(unsigned e, int& pix, float& w) {
    pix = (int)(e & 0x1FFFFu);
    w = (float)(e >> 17) * (1.0f / 32767.0f);
}

// ---------------- permutohedral embedding (matches reference op-for-op, f32) ----------------
template<int D>
__device__ void perm_embed(const float* f, float* bary, unsigned long long* pk) {
    constexpr int D1 = D + 1;
    float cf[D];
    #pragma unroll
    for (int i = 0; i < D; i++) {
        double s = sqrt(2.0 / 3.0) * (double)D1 / sqrt((double)((i + 1) * (i + 2)));
        cf[i] = f[i] * (float)s;
    }
    float csum[D];
    float acc = 0.f;
    #pragma unroll
    for (int i = D - 1; i >= 0; i--) { acc += cf[i]; csum[i] = acc; }
    float el[D1];
    el[0] = csum[0];
    #pragma unroll
    for (int i = 1; i < D; i++) el[i] = csum[i] - (float)i * cf[i - 1];
    el[D] = -(float)D * cf[D - 1];
    const float down = 1.0f / (float)D1;
    float rem0[D1]; int rank[D1]; int ssum = 0;
    #pragma unroll
    for (int i = 0; i < D1; i++) {
        float rd = rintf(el[i] * down);
        rem0[i] = rd * (float)D1;
        ssum += (int)rd;
    }
    float diff[D1];
    #pragma unroll
    for (int i = 0; i < D1; i++) diff[i] = el[i] - rem0[i];
    #pragma unroll
    for (int i = 0; i < D1; i++) {
        int r = 0;
        #pragma unroll
        for (int j = 0; j < D1; j++)
            r += (diff[j] > diff[i]) || ((diff[j] == diff[i]) && (j < i));
        rank[i] = r + ssum;
    }
    #pragma unroll
    for (int i = 0; i < D1; i++) {
        if (rank[i] < 0)      { rank[i] += D1; rem0[i] += (float)D1; }
        else if (rank[i] > D) { rank[i] -= D1; rem0[i] -= (float)D1; }
    }
    float b[D + 2];
    #pragma unroll
    for (int i = 0; i < D + 2; i++) b[i] = 0.f;
    #pragma unroll
    for (int i = 0; i < D1; i++) b[D - rank[i]]     += (el[i] - rem0[i]) * down;
    #pragma unroll
    for (int i = 0; i < D1; i++) b[D + 1 - rank[i]] -= (el[i] - rem0[i]) * down;
    b[0] += 1.0f + b[D + 1];
    #pragma unroll
    for (int i = 0; i < D1; i++) bary[i] = b[i];
    int key0[D];
    #pragma unroll
    for (int i = 0; i < D; i++) key0[i] = (int)rintf(rem0[i]);
    #pragma unroll
    for (int r = 0; r < D1; r++) {
        unsigned long long p = 0;
        #pragma unroll
        for (int i = 0; i < D; i++) {
            int c = key0[i] + ((rank[i] < D1 - r) ? r : r - D1);
            p |= ((unsigned long long)((unsigned)(c + 2048) & 0xFFFu)) << (12 * i);
        }
        pk[r] = p;
    }
}

__device__ __forceinline__ int key_code(unsigned long long k) {
    int c0 = (int)(k & 0xFFFULL);
    int c1 = (int)((k >> 12) & 0xFFFULL);
    return ((c0 & 0xFF) << 8) | (c1 & 0xFF);
}

// ---------------- hash table (r11-proven plain CAS-first insert) ----------------
__device__ __forceinline__ int hash_insert(unsigned long long* hk, int tmask, unsigned long long k) {
    int slot = (int)(mix64(k) & (unsigned long long)tmask);
    while (true) {
        unsigned long long prev = atomicCAS(&hk[slot], EMPTY_KEY, k);
        if (prev == EMPTY_KEY || prev == k) return slot;
        slot = (slot + 1) & tmask;
    }
}
__device__ __forceinline__ int hash_lookup(const unsigned long long* hk, const int* hid,
                                           int tmask, unsigned long long k) {
    int slot = (int)(mix64(k) & (unsigned long long)tmask);
    while (true) {
        unsigned long long v = hk[slot];
        if (v == k) return hid[slot];
        if (v == EMPTY_KEY) return -1;
        slot = (slot + 1) & tmask;
    }
}

// ---------------- build kernels ----------------
// one launch builds both lattices (hk = unified table: [0,TBS) bilateral, [TBS,+TSS) spatial)
__global__ void build_both(const float* __restrict__ image, unsigned long long* hk,
                           int* os, float* wsv) {
    int i = blockIdx.x * blockDim.x + threadIdx.x;
    if (i < NPIX) {
        int x = i % IMW, y = i / IMW;
        float f[DB];
        f[0] = (float)x / 80.0f;
        f[1] = (float)y / 80.0f;
        f[2] = image[i * 3 + 0] / 13.0f;
        f[3] = image[i * 3 + 1] / 13.0f;
        f[4] = image[i * 3 + 2] / 13.0f;
        float bary[DB1]; unsigned long long pk[DB1];
        perm_embed<DB>(f, bary, pk);
        #pragma unroll
        for (int r = 0; r < DB1; r++) {
            wsv[i * DB1 + r] = bary[r];
            os[i * DB1 + r] = hash_insert(hk, TBS - 1, pk[r]);
        }
    } else if (i < 2 * NPIX) {
        int ip = i - NPIX;
        int x = ip % IMW, y = ip / IMW;
        float f[DS];
        f[0] = (float)x / 3.0f;
        f[1] = (float)y / 3.0f;
        float bary[DS1]; unsigned long long pk[DS1];
        perm_embed<DS>(f, bary, pk);
        #pragma unroll
        for (int r = 0; r < DS1; r++) {
            wsv[RB + ip * DS1 + r] = bary[r];
            os[RB + ip * DS1 + r] = hash_insert(hk + TBS, TSS - 1, pk[r]);
        }
    }
}

// hist over BOTH tables in one pass (hist halves: [0,NBUCK) b, [NBUCK,2N) s)
__global__ void hist_both(const unsigned long long* __restrict__ hk, int* hist) {
    int s = blockIdx.x * blockDim.x + threadIdx.x;
    if (s >= TBS + TSS) return;
    unsigned long long k = hk[s];
    if (k == EMPTY_KEY) return;
    int half = (s < TBS) ? 0 : NBUCK;
    atomicAdd(&hist[half + key_code(k)], 1);
}

// ---------------- barrier-free scan machinery ----------------
__global__ void scan_wave_partial(const int* __restrict__ count, int* incl, int* wsum, int n) {
    int idx = blockIdx.x * blockDim.x + threadIdx.x;
    int lane = threadIdx.x & 63;
    int v = (idx < n) ? count[idx] : 0;
    int s = v;
    #pragma unroll
    for (int d = 1; d < 64; d <<= 1) {
        int t = __shfl_up(s, d);
        if (lane >= d) s += t;
    }
    if (idx < n) incl[idx] = s;
    if (lane == 63) wsum[idx >> 6] = s;
}

__global__ void scan_partials_excl(int* w, int nw, int* total_out) {
    __shared__ int sh[256];
    __shared__ int run;
    if (threadIdx.x == 0) run = 0;
    __syncthreads();
    for (int basei = 0; basei < nw; basei += 256) {
        int idx = basei + threadIdx.x;
        int v = (idx < nw) ? w[idx] : 0;
        sh[threadIdx.x] = v;
        __syncthreads();
        for (int d = 1; d < 256; d <<= 1) {
            int t = (threadIdx.x >= d) ? sh[threadIdx.x - d] : 0;
            __syncthreads();
            sh[threadIdx.x] += t;
            __syncthreads();
        }
        int total = sh[255];
        if (idx < nw) w[idx] = run + sh[threadIdx.x] - v;
        __syncthreads();
        if (threadIdx.x == 0) run += total;
        __syncthreads();
    }
    if (total_out != nullptr && threadIdx.x == 0) *total_out = run;
}

__global__ void scan_finalize(int* off, const int* __restrict__ count,
                              const int* __restrict__ wsum, int n) {
    int idx = blockIdx.x * blockDim.x + threadIdx.x;
    if (idx < n) off[idx] = off[idx] - count[idx] + wsum[idx >> 6];
}

// ---------------- bucket-sorted compaction ----------------
__global__ void assign_both(const unsigned long long* __restrict__ hk, int* hid,
                            const int* __restrict__ histOff, int* histFill,
                            unsigned long long* uk_b, unsigned long long* uk_s) {
    int s = blockIdx.x * blockDim.x + threadIdx.x;
    if (s >= TBS + TSS) return;
    unsigned long long k = hk[s];
    if (k == EMPTY_KEY) return;
    int half = (s < TBS) ? 0 : NBUCK;
    int code = half + key_code(k);
    int id = histOff[code] + atomicAdd(&histFill[code], 1);
    hid[s] = id;
    if (s < TBS) uk_b[id] = k; else uk_s[id] = k;
}

// unified os remap + cntr histogram + per-entry rank capture
// (cntr slots: [0,RB) bilateral ids, [RB,RB+RS) spatial; rnk written coalesced)
__global__ void os_count_both(int* os, const int* __restrict__ hid, int* cntr, int* rnk) {
    int i = blockIdx.x * blockDim.x + threadIdx.x;
    if (i >= RB + RS) return;
    if (i < RB) {
        int id = hid[os[i]];
        os[i] = id;
        rnk[i] = atomicAdd(&cntr[id], 1);
    } else {
        int id = hid[TBS + os[i]];
        os[i] = id;
        rnk[i] = atomicAdd(&cntr[RB + id], 1);
    }
}

template<int D>
__global__ void build_neighbors(const unsigned long long* __restrict__ uk,
                                const unsigned long long* __restrict__ hk,
                                const int* __restrict__ hid,
                                int tmask, const int* cnt, int stride,
                                int* n1, int* n2) {
    int m = blockIdx.x * blockDim.x + threadIdx.x;
    if (m >= *cnt) return;
    unsigned long long k = uk[m];
    int c[D];
    #pragma unroll
    for (int i = 0; i < D; i++) c[i] = (int)((k >> (12 * i)) & 0xFFFULL) - 2048;
    for (int j = 0; j <= D; j++) {
        unsigned long long p1 = 0, p2 = 0;
        #pragma unroll
        for (int i = 0; i < D; i++) {
            int a = c[i] + ((i == j) ? D : -1);
            int b = c[i] + ((i == j) ? -D : 1);
            p1 |= ((unsigned long long)((unsigned)(a + 2048) & 0xFFFu)) << (12 * i);
            p2 |= ((unsigned long long)((unsigned)(b + 2048) & 0xFFFu)) << (12 * i);
        }
        n1[j * stride + m] = hash_lookup(hk, hid, tmask, p1);
        n2[j * stride + m] = hash_lookup(hk, hid, tmask, p2);
    }
}

// unified fill: pos derived from precomputed rank — NO atomics
__global__ void fill_both(const int* __restrict__ os, const float* __restrict__ wsv,
                          const int* __restrict__ off, const int* __restrict__ rnk,
                          unsigned* epw) {
    int idx = blockIdx.x * blockDim.x + threadIdx.x;
    if (idx >= RB + RS) return;
    int slot, pix;
    if (idx < RB) { slot = os[idx];        pix = idx / DB1; }
    else          { slot = RB + os[idx];   pix = (idx - RB) / DS1; }
    int pos = off[slot] + rnk[idx];
    epw[pos] = pack_ew(pix, wsv[idx]);
}

// ---------------- batched filter kernels (fp16 storage, fp32 math) ----------------
__global__ void gather_both_h(const uint2* __restrict__ Qh, const int* __restrict__ off,
                              const int* __restrict__ cntr, const unsigned* __restrict__ epw,
                              uint2* __restrict__ buf, const int* cnt) {
    int Mb = cnt[0], Ms = cnt[1];
    int totB = (Mb + 1) * CP4;
    int tot = totB + (Ms + 1) * CP4;
    int stride = gridDim.x * blockDim.x;
    for (int idx = blockIdx.x * blockDim.x + threadIdx.x; idx < tot; idx += stride) {
        int c4, o, slot;
        if (idx < totB) {
            int row = idx / CP4; c4 = idx - row * CP4;
            o = idx;
            slot = row ? (row - 1) : -1;
        } else {
            int t = idx - totB;
            int row = t / CP4; c4 = t - row * CP4;
            o = (RB + 1 + row) * CP4 + c4;
            slot = row ? (RB + row - 1) : -1;
        }
        float4 acc = make_float4(0.f, 0.f, 0.f, 0.f);
        if (slot >= 0) {
            int s = off[slot], e = s + cntr[slot];
            for (int t = s; t < e; t++) {
                int pix; float w;
                unpack_ew(epw[t], pix, w);
                float4 v = u2f(Qh[(size_t)pix * CP4 + c4]);
                acc.x += w * v.x; acc.y += w * v.y; acc.z += w * v.z; acc.w += w * v.w;
            }
        }
        buf[o] = f2u(acc);
    }
}

__global__ void blur_both_h(const uint2* __restrict__ in, uint2* __restrict__ out,
                            const int* __restrict__ n1b, const int* __restrict__ n2b,
                            const int* __restrict__ n1s, const int* __restrict__ n2s,
                            const int* cnt) {
    int Mb = cnt[0], Ms = cnt[1];
    int totB = (Mb + 1) * CP4;
    int tot = totB + (Ms + 1) * CP4;
    int stride = gridDim.x * blockDim.x;
    for (int idx = blockIdx.x * blockDim.x + threadIdx.x; idx < tot; idx += stride) {
        if (idx < totB) {
            int row = idx / CP4, c4 = idx - row * CP4;
            if (row == 0) { out[idx] = make_uint2(0u, 0u); continue; }
            int m = row - 1;
            float4 a = u2f(in[(size_t)(n1b[m] + 1) * CP4 + c4]);
            float4 b = u2f(in[(size_t)(n2b[m] + 1) * CP4 + c4]);
            float4 x = u2f(in[idx]);
            x.x += 0.5f * (a.x + b.x); x.y += 0.5f * (a.y + b.y);
            x.z += 0.5f * (a.z + b.z); x.w += 0.5f * (a.w + b.w);
            out[idx] = f2u(x);
        } else {
            int t = idx - totB;
            int row = t / CP4, c4 = t - row * CP4;
            int o = (RB + 1 + row) * CP4 + c4;
            if (row == 0) { out[o] = make_uint2(0u, 0u); continue; }
            int m = row - 1;
            float4 a = u2f(in[(size_t)(RB + 2 + n1s[m]) * CP4 + c4]);  // -1 -> sink RB+1
            float4 b = u2f(in[(size_t)(RB + 2 + n2s[m]) * CP4 + c4]);
            float4 x = u2f(in[o]);
            x.x += 0.5f * (a.x + b.x); x.y += 0.5f * (a.y + b.y);
            x.z += 0.5f * (a.z + b.z); x.w += 0.5f * (a.w + b.w);
            out[o] = f2u(x);
        }
    }
}

__global__ void blur_b_h(const uint2* __restrict__ in, uint2* __restrict__ out,
                         const int* __restrict__ n1, const int* __restrict__ n2,
                         const int* cnt) {
    int M = cnt[0];
    int total = (M + 1) * CP4;
    int stride = gridDim.x * blockDim.x;
    for (int idx = blockIdx.x * blockDim.x + threadIdx.x; idx < total; idx += stride) {
        int row = idx / CP4, c4 = idx - row * CP4;
        if (row == 0) { out[idx] = make_uint2(0u, 0u); continue; }
        int m = row - 1;
        float4 a = u2f(in[(size_t)(n1[m] + 1) * CP4 + c4]);
        float4 b = u2f(in[(size_t)(n2[m] + 1) * CP4 + c4]);
        float4 x = u2f(in[idx]);
        x.x += 0.5f * (a.x + b.x); x.y += 0.5f * (a.y + b.y);
        x.z += 0.5f * (a.z + b.z); x.w += 0.5f * (a.w + b.w);
        out[idx] = f2u(x);
    }
}

// ---- fp32 norm-chain versions (per-row threads) ----
__global__ void gather1_both(const int* __restrict__ off, const int* __restrict__ cntr,
                             const unsigned* __restrict__ epw, float* __restrict__ buf,
                             const int* cnt) {
    int Mb = cnt[0], Ms = cnt[1];
    int totB = Mb + 1;
    int tot = totB + Ms + 1;
    int stride = gridDim.x * blockDim.x;
    for (int r = blockIdx.x * blockDim.x + threadIdx.x; r < tot; r += stride) {
        int o, slot;
        if (r < totB) { o = r;              slot = r ? (r - 1) : -1; }
        else          { int t = r - totB; o = RB + 1 + t; slot = t ? (RB + t - 1) : -1; }
        float acc = 0.f;
        if (slot >= 0) {
            int s = off[slot], e = s + cntr[slot];
            for (int t = s; t < e; t++) acc += (float)(epw[t] >> 17) * (1.0f / 32767.0f);
        }
        buf[o] = acc;
    }
}

__global__ void blur1_both(const float* __restrict__ in, float* __restrict__ out,
                           const int* __restrict__ n1b, const int* __restrict__ n2b,
                           const int* __restrict__ n1s, const int* __restrict__ n2s,
                           const int* cnt) {
    int Mb = cnt[0], Ms = cnt[1];
    int totB = Mb + 1;
    int tot = totB + Ms + 1;
    int stride = gridDim.x * blockDim.x;
    for (int r = blockIdx.x * blockDim.x + threadIdx.x; r < tot; r += stride) {
        if (r < totB) {
            if (r == 0) { out[0] = 0.f; continue; }
            int m = r - 1;
            out[r] = in[r] + 0.5f * (in[n1b[m] + 1] + in[n2b[m] + 1]);
        } else {
            int t = r - totB;
            int o = RB + 1 + t;
            if (t == 0) { out[o] = 0.f; continue; }
            int m = t - 1;
            out[o] = in[o] + 0.5f * (in[RB + 2 + n1s[m]] + in[RB + 2 + n2s[m]]);
        }
    }
}

__global__ void blur1_b(const float* __restrict__ in, float* __restrict__ out,
                        const int* __restrict__ n1, const int* __restrict__ n2,
                        const int* cnt) {
    int M = cnt[0];
    int stride = gridDim.x * blockDim.x;
    for (int row = blockIdx.x * blockDim.x + threadIdx.x; row <= M; row += stride) {
        if (row == 0) { out[0] = 0.f; continue; }
        int m = row - 1;
        out[row] = in[row] + 0.5f * (in[n1[m] + 1] + in[n2[m] + 1]);
    }
}

// both norms in one pass (bilateral final in bufB, spatial final in bufS)
__global__ void slice_norm_both(const float* __restrict__ bufB, const float* __restrict__ bufS,
                                const int* __restrict__ osw, const float* __restrict__ wsv,
                                float* __restrict__ nbv, float* __restrict__ nsv,
                                float alphaB, float alphaS) {
    int i = blockIdx.x * blockDim.x + threadIdx.x;
    if (i >= NPIX) return;
    float sb = 0.f;
    #pragma unroll
    for (int r = 0; r < DB1; r++)
        sb += wsv[i * DB1 + r] * bufB[osw[i * DB1 + r] + 1];
    float ss = 0.f;
    #pragma unroll
    for (int r = 0; r < DS1; r++)
        ss += wsv[RB + i * DS1 + r] * bufS[RB + 2 + osw[RB + i * DS1 + r]];
    nbv[i] = alphaB * sb + 1e-20f;
    nsv[i] = alphaS * ss + 1e-20f;
}

// fused: slice(bilateral)+slice(spatial)+normalize+softmax -> Q (fp32) + Qh (fp16)
__global__ void slice_update(const float* __restrict__ U,
                             const uint2* __restrict__ bufB, const uint2* __restrict__ bufS,
                             const int* __restrict__ osw, const float* __restrict__ wsv,
                             const float* __restrict__ nbv, const float* __restrict__ nsv,
                             float* __restrict__ Q, uint2* __restrict__ Qh,
                             float alphaB, float alphaS, int use_msg) {
    int i = blockIdx.x * blockDim.x + threadIdx.x;
    if (i >= NPIX) return;
    float msg[24];
    #pragma unroll
    for (int t = 0; t < 24; t++) msg[t] = 0.f;
    if (use_msg) {
        float ib = 10.0f * alphaB / nbv[i];
        float is = 3.0f * alphaS / nsv[i];
        #pragma unroll
        for (int r = 0; r < DB1; r++) {
            float w = ib * wsv[i * DB1 + r];
            size_t base = (size_t)(osw[i * DB1 + r] + 1) * CP4;
            #pragma unroll
            for (int t = 0; t < CP4; t++) {
                float4 v = u2f(bufB[base + t]);
                msg[4 * t + 0] += w * v.x; msg[4 * t + 1] += w * v.y;
                msg[4 * t + 2] += w * v.z; msg[4 * t + 3] += w * v.w;
            }
        }
        #pragma unroll
        for (int r = 0; r < DS1; r++) {
            float w = is * wsv[RB + i * DS1 + r];
            size_t base = (size_t)(RB + 2 + osw[RB + i * DS1 + r]) * CP4;
            #pragma unroll
            for (int t = 0; t < CP4; t++) {
                float4 v = u2f(bufS[base + t]);
                msg[4 * t + 0] += w * v.x; msg[4 * t + 1] += w * v.y;
                msg[4 * t + 2] += w * v.z; msg[4 * t + 3] += w * v.w;
            }
        }
    }
    float mx = -1e30f;
    #pragma unroll
    for (int c = 0; c < NC; c++) {
        msg[c] = -U[i * NC + c] + msg[c];
        mx = fmaxf(mx, msg[c]);
    }
    float s = 0.f;
    #pragma unroll
    for (int c = 0; c < NC; c++) { float e = expf(msg[c] - mx); msg[c] = e; s += e; }
    float inv = 1.0f / s;
    #pragma unroll
    for (int c = 0; c < NC; c++) {
        msg[c] *= inv;
        Q[i * NC + c] = msg[c];
    }
    msg[21] = 0.f; msg[22] = 0.f; msg[23] = 0.f;
    #pragma unroll
    for (int t = 0; t < CP4; t++)
        Qh[i * CP4 + t] = f2u(make_float4(msg[4 * t], msg[4 * t + 1], msg[4 * t + 2], msg[4 * t + 3]));
}

// ---------------- host orchestration ----------------
extern "C" void kernel_launch(void* const* d_in, const int* in_sizes, int n_in,
                              void* d_out, int out_size, void* d_ws, size_t ws_size,
                              hipStream_t stream) {
    const float* U     = (const float*)d_in[0];
    const float* image = (const float*)d_in[1];
    float* Q = (float*)d_out;

    char* base = (char*)d_ws;
    size_t off = 0;
    auto alloc = [&](size_t bytes) -> void* {
        off = (off + 255) & ~(size_t)255;
        void* p = base + off; off += bytes; return p;
    };
    // unified per-entry arrays: [0,RB) bilateral, [RB,RB+RS) spatial
    int*   osw  = (int*)  alloc((size_t)(RB + RS) * 4);
    float* wsv  = (float*)alloc((size_t)(RB + RS) * 4);
    int*   rnk  = (int*)  alloc((size_t)(RB + RS) * 4);
    int*   n1_b = (int*)  alloc((size_t)DB1 * RB * 4);
    int*   n2_b = (int*)  alloc((size_t)DB1 * RB * 4);
    int*   n1_s = (int*)  alloc((size_t)DS1 * RS * 4);
    int*   n2_s = (int*)  alloc((size_t)DS1 * RS * 4);
    unsigned long long* uk_b = (unsigned long long*)alloc((size_t)RB * 8);
    unsigned long long* uk_s = (unsigned long long*)alloc((size_t)RS * 8);
    unsigned long long* hk = (unsigned long long*)alloc((size_t)(TBS + TSS) * 8);
    int*   hid  = (int*)  alloc((size_t)(TBS + TSS) * 4);
    int*   cnt  = (int*)  alloc(256);   // [0]=M_b, [1]=M_s
    int*   histOff = (int*)alloc((size_t)2 * NBUCK * 4);
    int*   wsums   = (int*)alloc((size_t)64 * 1024 * 4);
    int*   wsI     = (int*)alloc((size_t)16384 * 4);   // level-1 inclusive sums
    int*   ws2     = (int*)alloc((size_t)1024 * 4);    // level-2 sums
    int*   offv    = (int*)alloc((size_t)(RB + RS) * 4);
    // contiguous zero region: cntr | hist | histFill  (no fill array anymore)
    char*  zreg  = (char*)alloc((size_t)(RB + RS) * 4 + (size_t)2 * NBUCK * 8);
    int*   cntr     = (int*)zreg;
    int*   hist     = cntr + (RB + RS);
    int*   histFill = hist + 2 * NBUCK;
    size_t zbytes = (size_t)(RB + RS) * 4 + (size_t)2 * NBUCK * 8;
    unsigned* epw = (unsigned*)alloc((size_t)(RB + RS) * 4);   // packed 4B entries
    float* norm_b = (float*)alloc((size_t)NPIX * 4);
    float* norm_s = (float*)alloc((size_t)NPIX * 4);
    uint2* Qh   = (uint2*)alloc((size_t)NPIX * CP4 * 8);
    // combined lattice buffers: rows RB+RS+2 (bilateral [0,RB], spatial [RB+1,...])
    uint2* buf0 = (uint2*)alloc((size_t)(RB + RS + 2) * CP4 * 8);
    uint2* buf1 = (uint2*)alloc((size_t)(RB + RS + 2) * CP4 * 8);
    float* nbuf0 = (float*)alloc((size_t)(RB + RS + 2) * 4);
    float* nbuf1 = (float*)alloc((size_t)(RB + RS + 2) * 4);
    if (off > ws_size) return;

    const float ALPHA_B = (float)(1.0 / (1.0 + exp2(-(double)DB)));  // 32/33
    const float ALPHA_S = (float)(1.0 / (1.0 + exp2(-(double)DS)));  // 4/5

    constexpr int PG = 4096;

    // ---- 3 memsets ----
    hipMemsetAsync(cnt, 0, 16, stream);
    hipMemsetAsync(hk, 0xFF, (size_t)(TBS + TSS) * 8, stream);
    hipMemsetAsync(zreg, 0, zbytes, stream);

    // ---- build both lattices ----
    build_both<<<(2 * NPIX + 255) / 256, 256, 0, stream>>>(image, hk, osw, wsv);
    hist_both<<<(TBS + TSS) / 256, 256, 0, stream>>>(hk, hist);
    // compaction scans per table (ids start at 0 for each)
    scan_wave_partial<<<NBUCK / 256, 256, 0, stream>>>(hist, histOff, wsums, NBUCK);
    scan_partials_excl<<<1, 256, 0, stream>>>(wsums, NBUCK / 64, cnt + 0);
    scan_finalize<<<NBUCK / 256, 256, 0, stream>>>(histOff, hist, wsums, NBUCK);
    scan_wave_partial<<<NBUCK / 256, 256, 0, stream>>>(hist + NBUCK, histOff + NBUCK, wsums, NBUCK);
    scan_partials_excl<<<1, 256, 0, stream>>>(wsums, NBUCK / 64, cnt + 1);
    scan_finalize<<<NBUCK / 256, 256, 0, stream>>>(histOff + NBUCK, hist + NBUCK, wsums, NBUCK);
    assign_both<<<(TBS + TSS) / 256, 256, 0, stream>>>(hk, hid, histOff, histFill, uk_b, uk_s);
    os_count_both<<<(RB + RS) / 256, 256, 0, stream>>>(osw, hid, cntr, rnk);
    build_neighbors<DB><<<(RB + 255) / 256, 256, 0, stream>>>(uk_b, hk, hid, TBS - 1, cnt + 0, RB, n1_b, n2_b);
    build_neighbors<DS><<<(RS + 255) / 256, 256, 0, stream>>>(uk_s, hk + TBS, hid + TBS, TSS - 1, cnt + 1, RS, n1_s, n2_s);
    // unified offset scan over RB+RS id slots — hierarchical
    scan_wave_partial<<<(RB + RS) / 256, 256, 0, stream>>>(cntr, offv, wsums, RB + RS);
    scan_wave_partial<<<(NW1 + 255) / 256, 256, 0, stream>>>(wsums, wsI, ws2, NW1);
    scan_partials_excl<<<1, 256, 0, stream>>>(ws2, (NW1 + 63) / 64, nullptr);
    scan_finalize<<<(NW1 + 255) / 256, 256, 0, stream>>>(wsI, wsums, ws2, NW1);
    scan_finalize<<<(RB + RS) / 256, 256, 0, stream>>>(offv, cntr, wsI, RB + RS);
    fill_both<<<(RB + RS + 255) / 256, 256, 0, stream>>>(osw, wsv, offv, rnk, epw);

    // ---- norm filters (C=1, fp32), batched ----
    {
        gather1_both<<<1024, 256, 0, stream>>>(offv, cntr, epw, nbuf0, cnt);
        float* a = nbuf0; float* b = nbuf1;
        for (int j = 0; j < DS1; j++) {   // j=0..2: both chains
            blur1_both<<<1024, 256, 0, stream>>>(a, b,
                n1_b + (size_t)j * RB, n2_b + (size_t)j * RB,
                n1_s + (size_t)j * RS, n2_s + (size_t)j * RS, cnt);
            float* t = a; a = b; b = t;
        }
        // j=3..5: bilateral only — writes only rows [0,Mb]; spatial final stays in nbuf1.
        for (int j = DS1; j < DB1; j++) {
            blur1_b<<<1024, 256, 0, stream>>>(a, b, n1_b + (size_t)j * RB, n2_b + (size_t)j * RB, cnt);
            float* t = a; a = b; b = t;
        }
        // bilateral final in nbuf0 (6 swaps), spatial final in nbuf1 (3 swaps)
        slice_norm_both<<<(NPIX + 255) / 256, 256, 0, stream>>>(
            nbuf0, nbuf1, osw, wsv, norm_b, norm_s, ALPHA_B, ALPHA_S);
    }

    // ---- Q0 = softmax(-U) ----
    slice_update<<<(NPIX + 255) / 256, 256, 0, stream>>>(
        U, buf0, buf1, osw, wsv, norm_b, norm_s, Q, Qh, ALPHA_B, ALPHA_S, 0);

    // ---- 5 mean-field iterations ----
    for (int it = 0; it < 5; it++) {
        gather_both_h<<<PG, 256, 0, stream>>>(Qh, offv, cntr, epw, buf0, cnt);
        uint2* a = buf0; uint2* b = buf1;
        for (int j = 0; j < DS1; j++) {   // j=0..2: both chains in one launch
            blur_both_h<<<PG, 256, 0, stream>>>(a, b,
                n1_b + (size_t)j * RB, n2_b + (size_t)j * RB,
                n1_s + (size_t)j * RS, n2_s + (size_t)j * RS, cnt);
            uint2* t = a; a = b; b = t;
        }
        for (int j = DS1; j < DB1; j++) { // j=3..5: bilateral only
            blur_b_h<<<PG, 256, 0, stream>>>(a, b, n1_b + (size_t)j * RB, n2_b + (size_t)j * RB, cnt);
            uint2* t = a; a = b; b = t;
        }
        // bilateral final in buf0, spatial final in buf1
        slice_update<<<(NPIX + 255) / 256, 256, 0, stream>>>(
            U, buf0, buf1, osw, wsv, norm_b, norm_s, Q, Qh, ALPHA_B, ALPHA_S, 1);
    }
}